// Round 6
// baseline (4874056.641 us; speedup 1.0000x reference)
//
#include <hip/hip_runtime.h>

// OT Sinkhorn loss. B=4 images, N=1024 pts, 128x128 grid, 100 iters.
// R6: (1) data-as-flag sync -- u published with iteration-parity tag in
// mantissa LSB (<=1ulp); consumers poll their own value: detect+load = ONE
// LLC access, no flags. (2) constant CSR entry stream cached in LDS (halo
// cells = contiguous range). (3) fused setup + in-main finalize: 3 launches.
// R5 was 851us: latency chain (store drain + flag RT + poll + load) +
// per-iter L2->LDS dependent entry walk; traffic was NOT the bottleneck.

#define GRID_N 128
#define NCELL  16384
#define NPTS   1024
#define NIMG   4
#define WIN    7
#define WHALF  3
#define NITER  100
#define NBAND  16
#define TPB    512
#define VROWS  14
#define HCELLS (VROWS*GRID_N)   // 1792
#define EPI    (NPTS*49)        // 50176
#define ENT_CAP 10240           // LDS entry cache (expected ~5500/band)

#define C2   (-0.14426950408889634f)   // -log2(e)/10
#define EPSF 1e-16f

// ws layout (bytes)
#define WS_LOSS_B   0         // f32[4] + u32 done-counter @16
#define WS_U_B      64        // u32[4][1024] tagged u
#define WS_BOFS_B   16448     // u32[4][32] (17 used)
#define WS_PLIST_B  16960     // u32[4][1024] band-sorted pids
#define WS_COUNTS_B 33344     // u32[4][16384]
#define WS_OFFS_B   295488    // u32[4][16400]
#define OFF_STRIDE  16400
#define WS_ENTC_B   557888    // u32[4][50176] {K22|pid10} cell-major CSR
#define WS_TOTAL    1360704
#define ZERO_BYTES  32        // loss + done-counter only

#define AGENT __HIP_MEMORY_SCOPE_AGENT

__device__ __forceinline__ void window_of(float px, float py, int& r_lo, int& c_lo)
{
    int kc = (int)(px * 0.125f); kc = kc < 0 ? 0 : (kc > GRID_N-1 ? GRID_N-1 : kc);
    int kr = (int)(py * 0.125f); kr = kr < 0 ? 0 : (kr > GRID_N-1 ? GRID_N-1 : kr);
    c_lo = kc - WHALF; c_lo = c_lo < 0 ? 0 : (c_lo > GRID_N-WIN ? GRID_N-WIN : c_lo);
    r_lo = kr - WHALF; r_lo = r_lo < 0 ? 0 : (r_lo > GRID_N-WIN ? GRID_N-WIN : r_lo);
}

// ---- fused setup: zero counts -> count -> scan -> fill -> psort+u-init ----
__global__ __launch_bounds__(1024) void ot_setup_kernel(
    const float* __restrict__ pts, unsigned* __restrict__ ws_u32)
{
    const int img = blockIdx.x, t = threadIdx.x;
    unsigned* counts = ws_u32 + WS_COUNTS_B/4 + img*NCELL;
    unsigned* offs   = ws_u32 + WS_OFFS_B/4 + img*OFF_STRIDE;
    unsigned* entC   = ws_u32 + WS_ENTC_B/4 + img*EPI;

    __shared__ unsigned sc[1024];
    __shared__ unsigned cnt[16];
    __shared__ unsigned pos[17];

    // phase 0: zero counts
    {
        uint4 z = make_uint4(0,0,0,0);
        uint4* w4 = (uint4*)(counts + t*16);
#pragma unroll
        for (int j = 0; j < 4; ++j) w4[j] = z;
    }
    __syncthreads();

    // phase 1: count points covering each cell
    const float px = pts[(img*NPTS + t)*2 + 0];
    const float py = pts[(img*NPTS + t)*2 + 1];
    int r_lo, c_lo; window_of(px, py, r_lo, c_lo);
#pragma unroll
    for (int wy = 0; wy < WIN; ++wy)
#pragma unroll
        for (int wx = 0; wx < WIN; ++wx)
            atomicAdd(&counts[(r_lo+wy)*GRID_N + c_lo + wx], 1u);
    __syncthreads();

    // phase 2: exclusive scan counts -> offs
    {
        unsigned c[16];
        const uint4* c4 = (const uint4*)(counts + t*16);
#pragma unroll
        for (int j = 0; j < 4; ++j) {
            uint4 v = c4[j];
            c[j*4+0]=v.x; c[j*4+1]=v.y; c[j*4+2]=v.z; c[j*4+3]=v.w;
        }
        unsigned s = 0;
#pragma unroll
        for (int k = 0; k < 16; ++k) s += c[k];
        sc[t] = s; __syncthreads();
        for (int d = 1; d < 1024; d <<= 1) {
            unsigned x = (t >= d) ? sc[t-d] : 0u;
            __syncthreads();
            sc[t] += x;
            __syncthreads();
        }
        unsigned run = sc[t] - s;
#pragma unroll
        for (int k = 0; k < 16; ++k) { offs[t*16+k] = run; run += c[k]; }
        if (t == 1023) offs[NCELL] = run;   // = 50176
    }
    __syncthreads();

    // phase 3: fill cell-major entries {K22|pid10}; drains counts
#pragma unroll
    for (int wy = 0; wy < WIN; ++wy) {
        float dy = py - (float)(8*(r_lo+wy) + 4);
#pragma unroll
        for (int wx = 0; wx < WIN; ++wx) {
            float dx = px - (float)(8*(c_lo+wx) + 4);
            float K = exp2f(C2 * (dx*dx + dy*dy));
            unsigned Kb = __float_as_uint(K);
            unsigned e = ((Kb + 0x200u) & 0xFFFFFC00u) | (unsigned)t;
            int cell = (r_lo+wy)*GRID_N + c_lo + wx;
            unsigned old = atomicSub(&counts[cell], 1u);
            entC[offs[cell] + old - 1u] = e;
        }
    }
    __syncthreads();

    // phase 4: counting-sort by band; init tagged u (tag=1, never matches
    // iter-0-produced tag 0)
    if (t < 16) cnt[t] = 0;
    __syncthreads();
    int kr = (int)(py * 0.125f); kr = kr < 0 ? 0 : (kr > 127 ? 127 : kr);
    int b = kr >> 3;
    atomicAdd(&cnt[b], 1u);
    __syncthreads();
    if (t == 0) {
        unsigned run = 0;
        for (int i = 0; i < 16; ++i) { pos[i] = run; run += cnt[i]; }
        pos[16] = run;
    }
    __syncthreads();
    unsigned* bofs = ws_u32 + WS_BOFS_B/4 + img*32;
    if (t < 17) bofs[t] = pos[t];
    __syncthreads();
    unsigned slot = atomicAdd(&pos[b], 1u);
    ws_u32[WS_PLIST_B/4 + img*NPTS + slot] = (unsigned)t;
    unsigned a_tag = (__float_as_uint(1.0f/(float)NPTS) & ~1u) | 1u;
    ws_u32[WS_U_B/4 + img*NPTS + t] = a_tag;
}

// ---- poll own value until parity tag matches (data IS the flag) ----
__device__ __forceinline__ float poll_u(const unsigned* addr, unsigned tgt)
{
    unsigned w = __hip_atomic_load(addr, __ATOMIC_RELAXED, AGENT);
    int spins = 0;
    while ((w & 1u) != tgt) {
        __builtin_amdgcn_s_sleep(1);
        w = __hip_atomic_load(addr, __ATOMIC_RELAXED, AGENT);
        if (++spins > (1<<22)) break;   // safety net; never hit if logic sound
    }
    return __uint_as_float(w);
}

// ---- main: 64 WGs (4 img x 16 bands); LDS entry cache, tagged-u sync ----
__global__ __launch_bounds__(TPB) void ot_main_kernel(
    const float* __restrict__ dens, const float* __restrict__ pts,
    unsigned* __restrict__ ws_u32, float* __restrict__ out)
{
    const int img = (int)blockIdx.x >> 4, bnd = (int)blockIdx.x & 15;
    const int t = threadIdx.x;
    float* ws_f = (float*)ws_u32;

    float*    loss  = ws_f;
    unsigned* u_gu  = ws_u32 + WS_U_B/4 + img*NPTS;
    const unsigned* bofs  = ws_u32 + WS_BOFS_B/4 + img*32;
    const unsigned* plist = ws_u32 + WS_PLIST_B/4 + img*NPTS;
    const unsigned* offs  = ws_u32 + WS_OFFS_B/4 + img*OFF_STRIDE;
    const unsigned* entC  = ws_u32 + WS_ENTC_B/4 + img*EPI;

    __shared__ float    u_lds[NPTS];
    __shared__ float    v_loc[HCELLS];    // rows (8*bnd-3)..(8*bnd+10)
    __shared__ unsigned ent_l[ENT_CAP];
    __shared__ float    red[8];

    const int rowbase = bnd*8 - 3;
    const int row0 = rowbase < 0 ? 0 : rowbase;
    const int row1 = (rowbase + VROWS) > GRID_N ? GRID_N : (rowbase + VROWS);
    const unsigned e0 = offs[row0*GRID_N];
    const unsigned e1 = offs[row1*GRID_N];
    const int n_ent = (int)(e1 - e0);

    // copy constant entry stream into LDS (contiguous CSR range)
    for (int i = t; i < n_ent && i < ENT_CAP; i += TPB) ent_l[i] = entC[e0 + i];

    // ---- static cell side: up to 4 halo cells/thread (stride TPB) ----
    int cofs[4], ccnt[4], cvi[4]; float cb[4];
#pragma unroll
    for (int k = 0; k < 4; ++k) {
        int hc = t + k*TPB;            // 0..2047; valid < 1792
        ccnt[k] = 0; cvi[k] = 0; cb[k] = 0.f; cofs[k] = 0;
        if (hc < HCELLS) {
            int grow = rowbase + (hc >> 7);
            if (grow >= 0 && grow < GRID_N) {
                int gc = grow*GRID_N + (hc & 127);
                unsigned oA = offs[gc], oB = offs[gc+1];
                cofs[k] = (int)(oA - e0); ccnt[k] = (int)(oB - oA);
                cb[k] = dens[img*NCELL + gc];
                cvi[k] = hc;
            }
        }
    }

    // ---- static point side: 4 threads/point ----
    const int p0 = (int)bofs[bnd], p1 = (int)bofs[bnd+1];
    const int npts = p1 - p0;
    const int sub = t & 3;
    const int idx = t >> 2;
    int mypid = -1, km = 0;
    float Kq[13], Kd2[13];
    int   cq[13];
    if (idx < npts && idx < 128) {
        mypid = (int)plist[p0 + idx];
        float px = pts[(img*NPTS + mypid)*2 + 0];
        float py = pts[(img*NPTS + mypid)*2 + 1];
        int r_lo, c_lo; window_of(px, py, r_lo, c_lo);
        int k = 0;
#pragma unroll
        for (int q = 0; q < 49; ++q) {
            if ((q & 3) == sub) {
                int wy = q / 7, wx = q % 7;
                float dx = px - (float)(8*(c_lo+wx) + 4);
                float dy = py - (float)(8*(r_lo+wy) + 4);
                float d2 = dx*dx + dy*dy;
                float K = exp2f(C2 * d2);
                Kq[k] = K; Kd2[k] = K * d2;
                cq[k] = (r_lo + wy - rowbase)*GRID_N + (c_lo + wx);
                ++k;
            }
        }
        km = k;   // 13 or 12
    }
    const int lo = (int)bofs[bnd > 0 ? bnd-1 : 0];
    const int hi = (int)bofs[bnd < 15 ? bnd+2 : 16];
    const float A = 1.0f / (float)NPTS;

    u_lds[t] = A; u_lds[t + TPB] = A;
    float li_acc = 0.f;

    for (int it = 0; it < NITER; ++it) {
        if (it > 0) {
            // stage neighbor-band u: poll parity of producing iter (it-1)
            unsigned tgt = (unsigned)((it - 1) & 1);
            for (int i = lo + t; i < p0; i += TPB) {
                unsigned pid = plist[i];
                u_lds[pid] = poll_u(u_gu + pid, tgt);
            }
            for (int i = p1 + t; i < hi; i += TPB) {
                unsigned pid = plist[i];
                u_lds[pid] = poll_u(u_gu + pid, tgt);
            }
        }
        __syncthreads();

        // ---- phase A (redundant halo): v_loc = b / (K^T u + eps) ----
#pragma unroll
        for (int k = 0; k < 4; ++k) {
            int cn = ccnt[k];
            if (cn > 0) {
                float s = 0.f;
                int le = cofs[k];
                if (le + cn <= ENT_CAP) {
                    for (int e = 0; e < cn; ++e) {
                        unsigned E = ent_l[le + e];
                        s = fmaf(__uint_as_float(E & 0xFFFFFC00u), u_lds[E & 0x3FFu], s);
                    }
                } else {
                    for (int e = 0; e < cn; ++e) {   // overflow: L2 path
                        unsigned E = entC[e0 + le + e];
                        s = fmaf(__uint_as_float(E & 0xFFFFFC00u), u_lds[E & 0x3FFu], s);
                    }
                }
                v_loc[cvi[k]] = cb[k] / (s + EPSF);
            }
        }
        __syncthreads();

        // ---- phase B: u = A / (K v + eps); publish with parity tag ----
        if (mypid >= 0) {
            float kv = 0.f, kd = 0.f;
#pragma unroll
            for (int k = 0; k < 13; ++k) {
                if (k < km) {
                    float vj = v_loc[cq[k]];
                    kv = fmaf(Kq[k],  vj, kv);
                    kd = fmaf(Kd2[k], vj, kd);
                }
            }
            kv += __shfl_xor(kv, 1); kv += __shfl_xor(kv, 2);
            float u_new = A / (kv + EPSF);
            if (sub == 0) {
                u_lds[mypid] = u_new;
                unsigned pub = (__float_as_uint(u_new) & ~1u) | ((unsigned)it & 1u);
                __hip_atomic_store(u_gu + mypid, pub, __ATOMIC_RELAXED, AGENT);
            }
            if (it == NITER-1) {
                kd += __shfl_xor(kd, 1); kd += __shfl_xor(kd, 2);
                if (sub == 0) li_acc += u_new * kd;
            }
        }
        // rare overflow (band with >128 points): compute K inline
        for (int base2 = 128; base2 < npts; base2 += 128) {
            int idx2 = base2 + idx;
            if (idx2 < npts) {
                int pid2 = (int)plist[p0 + idx2];
                float px = pts[(img*NPTS + pid2)*2 + 0];
                float py = pts[(img*NPTS + pid2)*2 + 1];
                int r_lo, c_lo; window_of(px, py, r_lo, c_lo);
                float kv = 0.f, kd = 0.f;
                for (int q = sub; q < 49; q += 4) {
                    int wy = q / 7, wx = q % 7;
                    float dx = px - (float)(8*(c_lo+wx) + 4);
                    float dy = py - (float)(8*(r_lo+wy) + 4);
                    float d2 = dx*dx + dy*dy;
                    float K = exp2f(C2 * d2);
                    float vj = v_loc[(r_lo + wy - rowbase)*GRID_N + c_lo + wx];
                    kv = fmaf(K, vj, kv); kd = fmaf(K*d2, vj, kd);
                }
                kv += __shfl_xor(kv, 1); kv += __shfl_xor(kv, 2);
                float u_new = A / (kv + EPSF);
                if (sub == 0) {
                    u_lds[pid2] = u_new;
                    unsigned pub = (__float_as_uint(u_new) & ~1u) | ((unsigned)it & 1u);
                    __hip_atomic_store(u_gu + pid2, pub, __ATOMIC_RELAXED, AGENT);
                }
                if (it == NITER-1) {
                    kd += __shfl_xor(kd, 1); kd += __shfl_xor(kd, 2);
                    if (sub == 0) li_acc += u_new * kd;
                }
            }
        }
        __syncthreads();
    }

    // ---- loss reduction + last-WG finalize ----
#pragma unroll
    for (int o = 32; o > 0; o >>= 1) li_acc += __shfl_down(li_acc, o);
    if ((t & 63) == 0) red[t >> 6] = li_acc;
    __syncthreads();
    if (t == 0) {
        float s = 0.f;
#pragma unroll
        for (int w = 0; w < 8; ++w) s += red[w];
        atomicAdd(&loss[img], s);
        unsigned done = __hip_atomic_fetch_add(ws_u32 + 4, 1u,
                                               __ATOMIC_ACQ_REL, AGENT);
        if (done == (unsigned)(NIMG*NBAND - 1)) {
            float tot = 0.f;
#pragma unroll
            for (int i = 0; i < 4; ++i)
                tot += __hip_atomic_load(ws_f + i, __ATOMIC_RELAXED, AGENT);
            out[0] = tot;
            out[1] = tot;
            out[2] = 0.f;
        }
    }
}

// ---- fallback (ws too small): R1-verified single-kernel path ----
__global__ __launch_bounds__(1024) void ot_fallback_kernel(
    const float* __restrict__ dens, const float* __restrict__ pts,
    float* __restrict__ out)
{
    const int img = blockIdx.x, t = threadIdx.x;
    __shared__ float sv[NCELL];
    __shared__ float redf[16];

    const float px = pts[(size_t)img*NPTS*2 + t*2 + 0];
    const float py = pts[(size_t)img*NPTS*2 + t*2 + 1];
    int r_lo, c_lo; window_of(px, py, r_lo, c_lo);

    float dx2[WIN], dy2[WIN];
#pragma unroll
    for (int j = 0; j < WIN; ++j) {
        float dx = px - (float)(8*(c_lo+j) + 4);
        float dy = py - (float)(8*(r_lo+j) + 4);
        dx2[j] = dx*dx; dy2[j] = dy*dy;
    }
    float K[WIN*WIN];
#pragma unroll
    for (int wy = 0; wy < WIN; ++wy)
#pragma unroll
        for (int wx = 0; wx < WIN; ++wx)
            K[wy*WIN+wx] = exp2f(C2 * (dx2[wx] + dy2[wy]));

    const int lbase = r_lo*GRID_N + c_lo;
    float breg[16];
    const float4* d4 = (const float4*)(dens + (size_t)img*NCELL + t*16);
#pragma unroll
    for (int j = 0; j < 4; ++j) {
        float4 v = d4[j];
        breg[j*4+0]=v.x; breg[j*4+1]=v.y; breg[j*4+2]=v.z; breg[j*4+3]=v.w;
    }
    const float A = 1.0f/(float)NPTS;
    float u = A;
    float4* sv4 = (float4*)sv;
    for (int it = 0; it < NITER; ++it) {
        __syncthreads();
#pragma unroll
        for (int j = 0; j < 4; ++j) sv4[t*4+j] = make_float4(0.f,0.f,0.f,0.f);
        __syncthreads();
#pragma unroll
        for (int wy = 0; wy < WIN; ++wy)
#pragma unroll
            for (int wx = 0; wx < WIN; ++wx)
                atomicAdd(&sv[lbase + wy*GRID_N + wx], u * K[wy*WIN+wx]);
        __syncthreads();
#pragma unroll
        for (int j = 0; j < 16; ++j) { int c = t*16+j; sv[c] = breg[j] / (sv[c] + EPSF); }
        __syncthreads();
        float kv = 0.f;
#pragma unroll
        for (int wy = 0; wy < WIN; ++wy)
#pragma unroll
            for (int wx = 0; wx < WIN; ++wx)
                kv = fmaf(K[wy*WIN+wx], sv[lbase + wy*GRID_N + wx], kv);
        u = A / (kv + EPSF);
    }
    float li = 0.f;
#pragma unroll
    for (int wy = 0; wy < WIN; ++wy)
#pragma unroll
        for (int wx = 0; wx < WIN; ++wx)
            li = fmaf(K[wy*WIN+wx] * (dx2[wx]+dy2[wy]), sv[lbase + wy*GRID_N + wx], li);
    li *= u;
#pragma unroll
    for (int o = 32; o > 0; o >>= 1) li += __shfl_down(li, o);
    if ((t & 63) == 0) redf[t >> 6] = li;
    __syncthreads();
    if (t == 0) {
        float s = 0.f;
#pragma unroll
        for (int w = 0; w < 16; ++w) s += redf[w];
        atomicAdd(&out[0], s);
        atomicAdd(&out[1], s);
    }
}

extern "C" void kernel_launch(void* const* d_in, const int* in_sizes, int n_in,
                              void* d_out, int out_size, void* d_ws, size_t ws_size,
                              hipStream_t stream)
{
    const float* dens = (const float*)d_in[0];   // [4,1,128,128]
    const float* pts  = (const float*)d_in[2];   // [4,1024,2]
    float* out = (float*)d_out;
    unsigned* ws_u32 = (unsigned*)d_ws;

    if (ws_size < (size_t)WS_TOTAL) {   // insurance: slow-but-correct path
        hipMemsetAsync(d_out, 0, 3*sizeof(float), stream);
        ot_fallback_kernel<<<NIMG, 1024, 0, stream>>>(dens, pts, out);
        return;
    }

    hipMemsetAsync(d_ws, 0, ZERO_BYTES, stream);   // loss + done-counter
    ot_setup_kernel<<<NIMG, 1024, 0, stream>>>(pts, ws_u32);
    ot_main_kernel <<<NIMG*NBAND, TPB, 0, stream>>>(dens, pts, ws_u32, out);
}

// Round 7
// 885.099 us; speedup vs baseline: 5506.7895x; 5506.7895x over previous
//
#include <hip/hip_runtime.h>

// OT Sinkhorn loss. B=4 images, N=1024 pts, 128x128 grid, 100 iters.
// R7 = R5's PROVEN release/acquire flag sync (one flag/band/iter) +
// R6's LDS entry cache (phase A pure-LDS; post-acquire global reads are
// only ~128 coalesced u loads). R6's parity-equality poll DEADLOCKED
// pairwise (resolved by timeouts -> 4.9s); R5's flag sync never did.

#define GRID_N 128
#define NCELL  16384
#define NPTS   1024
#define NIMG   4
#define WIN    7
#define WHALF  3
#define NITER  100
#define NBAND  16
#define TPB    512
#define VROWS  14
#define HCELLS (VROWS*GRID_N)   // 1792
#define EPI    (NPTS*49)        // 50176
#define ENT_CAP 10240           // LDS entry cache (expected ~5500/band)

#define C2   (-0.14426950408889634f)   // -log2(e)/10
#define EPSF 1e-16f

// ws layout (bytes)
#define WS_LOSS_B   0         // f32[4] + u32 done-counter @16
#define WS_FLAGS_B  64        // u32[4][16][16] (64B stride per flag)
#define WS_U_B      4160      // f32[4][1024]
#define WS_BOFS_B   20544     // u32[4][32] (17 used)
#define WS_PLIST_B  21056     // u32[4][1024] band-sorted pids
#define WS_COUNTS_B 37440     // u32[4][16384]
#define WS_OFFS_B   299584    // u32[4][16400]
#define OFF_STRIDE  16400
#define WS_ENTC_B   561984    // u32[4][50176] {K22|pid10} cell-major CSR
#define WS_TOTAL    1364800
#define ZERO_BYTES  4160      // loss + done-counter + flags

#define AGENT __HIP_MEMORY_SCOPE_AGENT

__device__ __forceinline__ void window_of(float px, float py, int& r_lo, int& c_lo)
{
    int kc = (int)(px * 0.125f); kc = kc < 0 ? 0 : (kc > GRID_N-1 ? GRID_N-1 : kc);
    int kr = (int)(py * 0.125f); kr = kr < 0 ? 0 : (kr > GRID_N-1 ? GRID_N-1 : kr);
    c_lo = kc - WHALF; c_lo = c_lo < 0 ? 0 : (c_lo > GRID_N-WIN ? GRID_N-WIN : c_lo);
    r_lo = kr - WHALF; r_lo = r_lo < 0 ? 0 : (r_lo > GRID_N-WIN ? GRID_N-WIN : r_lo);
}

// ---- fused setup: zero counts -> count -> scan -> fill -> psort+u-init ----
__global__ __launch_bounds__(1024) void ot_setup_kernel(
    const float* __restrict__ pts, unsigned* __restrict__ ws_u32)
{
    const int img = blockIdx.x, t = threadIdx.x;
    unsigned* counts = ws_u32 + WS_COUNTS_B/4 + img*NCELL;
    unsigned* offs   = ws_u32 + WS_OFFS_B/4 + img*OFF_STRIDE;
    unsigned* entC   = ws_u32 + WS_ENTC_B/4 + img*EPI;

    __shared__ unsigned sc[1024];
    __shared__ unsigned cnt[16];
    __shared__ unsigned pos[17];

    // phase 0: zero counts
    {
        uint4 z = make_uint4(0,0,0,0);
        uint4* w4 = (uint4*)(counts + t*16);
#pragma unroll
        for (int j = 0; j < 4; ++j) w4[j] = z;
    }
    __syncthreads();

    // phase 1: count points covering each cell
    const float px = pts[(img*NPTS + t)*2 + 0];
    const float py = pts[(img*NPTS + t)*2 + 1];
    int r_lo, c_lo; window_of(px, py, r_lo, c_lo);
#pragma unroll
    for (int wy = 0; wy < WIN; ++wy)
#pragma unroll
        for (int wx = 0; wx < WIN; ++wx)
            atomicAdd(&counts[(r_lo+wy)*GRID_N + c_lo + wx], 1u);
    __syncthreads();

    // phase 2: exclusive scan counts -> offs
    {
        unsigned c[16];
        const uint4* c4 = (const uint4*)(counts + t*16);
#pragma unroll
        for (int j = 0; j < 4; ++j) {
            uint4 v = c4[j];
            c[j*4+0]=v.x; c[j*4+1]=v.y; c[j*4+2]=v.z; c[j*4+3]=v.w;
        }
        unsigned s = 0;
#pragma unroll
        for (int k = 0; k < 16; ++k) s += c[k];
        sc[t] = s; __syncthreads();
        for (int d = 1; d < 1024; d <<= 1) {
            unsigned x = (t >= d) ? sc[t-d] : 0u;
            __syncthreads();
            sc[t] += x;
            __syncthreads();
        }
        unsigned run = sc[t] - s;
#pragma unroll
        for (int k = 0; k < 16; ++k) { offs[t*16+k] = run; run += c[k]; }
        if (t == 1023) offs[NCELL] = run;   // = 50176
    }
    __syncthreads();

    // phase 3: fill cell-major entries {K22|pid10}; drains counts
#pragma unroll
    for (int wy = 0; wy < WIN; ++wy) {
        float dy = py - (float)(8*(r_lo+wy) + 4);
#pragma unroll
        for (int wx = 0; wx < WIN; ++wx) {
            float dx = px - (float)(8*(c_lo+wx) + 4);
            float K = exp2f(C2 * (dx*dx + dy*dy));
            unsigned Kb = __float_as_uint(K);
            unsigned e = ((Kb + 0x200u) & 0xFFFFFC00u) | (unsigned)t;
            int cell = (r_lo+wy)*GRID_N + c_lo + wx;
            unsigned old = atomicSub(&counts[cell], 1u);
            entC[offs[cell] + old - 1u] = e;
        }
    }
    __syncthreads();

    // phase 4: counting-sort by band; init u = 1/N
    if (t < 16) cnt[t] = 0;
    __syncthreads();
    int kr = (int)(py * 0.125f); kr = kr < 0 ? 0 : (kr > 127 ? 127 : kr);
    int b = kr >> 3;
    atomicAdd(&cnt[b], 1u);
    __syncthreads();
    if (t == 0) {
        unsigned run = 0;
        for (int i = 0; i < 16; ++i) { pos[i] = run; run += cnt[i]; }
        pos[16] = run;
    }
    __syncthreads();
    unsigned* bofs = ws_u32 + WS_BOFS_B/4 + img*32;
    if (t < 17) bofs[t] = pos[t];
    __syncthreads();
    unsigned slot = atomicAdd(&pos[b], 1u);
    ws_u32[WS_PLIST_B/4 + img*NPTS + slot] = (unsigned)t;
    ((float*)ws_u32)[WS_U_B/4 + img*NPTS + t] = 1.0f / (float)NPTS;
}

// ---- neighbor flag wait: lanes 0/1 poll bnd-1 / bnd+1 (ACQUIRE) ----
__device__ __forceinline__ void wait_nbrs(unsigned* fl, int bnd, unsigned target)
{
    int lane = threadIdx.x;            // called with t < 64
    int nb = (lane == 0) ? bnd - 1 : (lane == 1 ? bnd + 1 : bnd);
    nb = (nb < 0 || nb > 15) ? bnd : nb;
    unsigned* p = fl + nb*16;
    int spins = 0;
    while (__hip_atomic_load(p, __ATOMIC_ACQUIRE, AGENT) < target) {
        __builtin_amdgcn_s_sleep(1);
        if (++spins > (1<<21)) break;  // safety: never triggers (R4/R5 proven)
    }
}

// ---- main: 64 WGs (4 img x 16 bands); LDS entry cache + flag sync ----
__global__ __launch_bounds__(TPB) void ot_main_kernel(
    const float* __restrict__ dens, const float* __restrict__ pts,
    unsigned* __restrict__ ws_u32, float* __restrict__ out)
{
    const int img = (int)blockIdx.x >> 4, bnd = (int)blockIdx.x & 15;
    const int t = threadIdx.x;
    float* ws_f = (float*)ws_u32;

    float*    loss  = ws_f;
    unsigned* fB    = ws_u32 + WS_FLAGS_B/4 + img*256;
    float*    u_g   = ws_f + WS_U_B/4 + img*NPTS;
    const unsigned* bofs  = ws_u32 + WS_BOFS_B/4 + img*32;
    const unsigned* plist = ws_u32 + WS_PLIST_B/4 + img*NPTS;
    const unsigned* offs  = ws_u32 + WS_OFFS_B/4 + img*OFF_STRIDE;
    const unsigned* entC  = ws_u32 + WS_ENTC_B/4 + img*EPI;

    __shared__ float    u_lds[NPTS];
    __shared__ float    v_loc[HCELLS];    // rows (8*bnd-3)..(8*bnd+10)
    __shared__ unsigned ent_l[ENT_CAP];
    __shared__ float    red[8];

    const int rowbase = bnd*8 - 3;
    const int row0 = rowbase < 0 ? 0 : rowbase;
    const int row1 = (rowbase + VROWS) > GRID_N ? GRID_N : (rowbase + VROWS);
    const unsigned e0 = offs[row0*GRID_N];
    const unsigned e1 = offs[row1*GRID_N];
    const int n_ent = (int)(e1 - e0);

    // copy constant entry stream into LDS (contiguous CSR range)
    for (int i = t; i < n_ent && i < ENT_CAP; i += TPB) ent_l[i] = entC[e0 + i];

    // ---- static cell side: up to 4 halo cells/thread (stride TPB) ----
    int cofs[4], ccnt[4], cvi[4]; float cb[4];
#pragma unroll
    for (int k = 0; k < 4; ++k) {
        int hc = t + k*TPB;            // 0..2047; valid < 1792
        ccnt[k] = 0; cvi[k] = 0; cb[k] = 0.f; cofs[k] = 0;
        if (hc < HCELLS) {
            int grow = rowbase + (hc >> 7);
            if (grow >= 0 && grow < GRID_N) {
                int gc = grow*GRID_N + (hc & 127);
                unsigned oA = offs[gc], oB = offs[gc+1];
                cofs[k] = (int)(oA - e0); ccnt[k] = (int)(oB - oA);
                cb[k] = dens[img*NCELL + gc];
                cvi[k] = hc;
            }
        }
    }

    // ---- static point side: 4 threads/point ----
    const int p0 = (int)bofs[bnd], p1 = (int)bofs[bnd+1];
    const int npts = p1 - p0;
    const int sub = t & 3;
    const int idx = t >> 2;
    int mypid = -1, km = 0;
    float Kq[13], Kd2[13];
    int   cq[13];
    if (idx < npts && idx < 128) {
        mypid = (int)plist[p0 + idx];
        float px = pts[(img*NPTS + mypid)*2 + 0];
        float py = pts[(img*NPTS + mypid)*2 + 1];
        int r_lo, c_lo; window_of(px, py, r_lo, c_lo);
        int k = 0;
#pragma unroll
        for (int q = 0; q < 49; ++q) {
            if ((q & 3) == sub) {
                int wy = q / 7, wx = q % 7;
                float dx = px - (float)(8*(c_lo+wx) + 4);
                float dy = py - (float)(8*(r_lo+wy) + 4);
                float d2 = dx*dx + dy*dy;
                float K = exp2f(C2 * d2);
                Kq[k] = K; Kd2[k] = K * d2;
                cq[k] = (r_lo + wy - rowbase)*GRID_N + (c_lo + wx);
                ++k;
            }
        }
        km = k;   // 13 or 12
    }
    const int lo = (int)bofs[bnd > 0 ? bnd-1 : 0];
    const int hi = (int)bofs[bnd < 15 ? bnd+2 : 16];
    const float A = 1.0f / (float)NPTS;

    u_lds[t] = A; u_lds[t + TPB] = A;
    float li_acc = 0.f;

    for (int it = 0; it < NITER; ++it) {
        if (it > 0) {
            // wait: neighbors published u^{it-1} (flag == it), ACQUIRE
            if (t < 64) wait_nbrs(fB, bnd, (unsigned)it);
            __syncthreads();
            // stage neighbor-band u (own band's u_lds kept locally)
            for (int i = lo + t; i < p0; i += TPB) {
                unsigned pid = plist[i];
                u_lds[pid] = __hip_atomic_load(u_g + pid, __ATOMIC_RELAXED, AGENT);
            }
            for (int i = p1 + t; i < hi; i += TPB) {
                unsigned pid = plist[i];
                u_lds[pid] = __hip_atomic_load(u_g + pid, __ATOMIC_RELAXED, AGENT);
            }
        }
        __syncthreads();

        // ---- phase A (redundant halo, pure LDS): v = b/(K^T u + eps) ----
#pragma unroll
        for (int k = 0; k < 4; ++k) {
            int cn = ccnt[k];
            if (cn > 0) {
                float s = 0.f;
                int le = cofs[k];
                if (le + cn <= ENT_CAP) {
                    for (int e = 0; e < cn; ++e) {
                        unsigned E = ent_l[le + e];
                        s = fmaf(__uint_as_float(E & 0xFFFFFC00u), u_lds[E & 0x3FFu], s);
                    }
                } else {
                    for (int e = 0; e < cn; ++e) {   // overflow: L2 path
                        unsigned E = entC[e0 + le + e];
                        s = fmaf(__uint_as_float(E & 0xFFFFFC00u), u_lds[E & 0x3FFu], s);
                    }
                }
                v_loc[cvi[k]] = cb[k] / (s + EPSF);
            }
        }
        __syncthreads();

        // ---- phase B: u = A / (K v + eps); store u (relaxed) ----
        if (mypid >= 0) {
            float kv = 0.f, kd = 0.f;
#pragma unroll
            for (int k = 0; k < 13; ++k) {
                if (k < km) {
                    float vj = v_loc[cq[k]];
                    kv = fmaf(Kq[k],  vj, kv);
                    kd = fmaf(Kd2[k], vj, kd);
                }
            }
            kv += __shfl_xor(kv, 1); kv += __shfl_xor(kv, 2);
            float u_new = A / (kv + EPSF);
            if (sub == 0) {
                u_lds[mypid] = u_new;
                __hip_atomic_store(u_g + mypid, u_new, __ATOMIC_RELAXED, AGENT);
            }
            if (it == NITER-1) {
                kd += __shfl_xor(kd, 1); kd += __shfl_xor(kd, 2);
                if (sub == 0) li_acc += u_new * kd;
            }
        }
        // rare overflow (band with >128 points): compute K inline
        for (int base2 = 128; base2 < npts; base2 += 128) {
            int idx2 = base2 + idx;
            if (idx2 < npts) {
                int pid2 = (int)plist[p0 + idx2];
                float px = pts[(img*NPTS + pid2)*2 + 0];
                float py = pts[(img*NPTS + pid2)*2 + 1];
                int r_lo, c_lo; window_of(px, py, r_lo, c_lo);
                float kv = 0.f, kd = 0.f;
                for (int q = sub; q < 49; q += 4) {
                    int wy = q / 7, wx = q % 7;
                    float dx = px - (float)(8*(c_lo+wx) + 4);
                    float dy = py - (float)(8*(r_lo+wy) + 4);
                    float d2 = dx*dx + dy*dy;
                    float K = exp2f(C2 * d2);
                    float vj = v_loc[(r_lo + wy - rowbase)*GRID_N + c_lo + wx];
                    kv = fmaf(K, vj, kv); kd = fmaf(K*d2, vj, kd);
                }
                kv += __shfl_xor(kv, 1); kv += __shfl_xor(kv, 2);
                float u_new = A / (kv + EPSF);
                if (sub == 0) {
                    u_lds[pid2] = u_new;
                    __hip_atomic_store(u_g + pid2, u_new, __ATOMIC_RELAXED, AGENT);
                }
                if (it == NITER-1) {
                    kd += __shfl_xor(kd, 1); kd += __shfl_xor(kd, 2);
                    if (sub == 0) li_acc += u_new * kd;
                }
            }
        }
        __syncthreads();   // all u stores issued before flag release
        if (t == 0)
            __hip_atomic_store(fB + bnd*16, (unsigned)(it+1), __ATOMIC_RELEASE, AGENT);
    }

    // ---- loss reduction + last-WG finalize ----
#pragma unroll
    for (int o = 32; o > 0; o >>= 1) li_acc += __shfl_down(li_acc, o);
    if ((t & 63) == 0) red[t >> 6] = li_acc;
    __syncthreads();
    if (t == 0) {
        float s = 0.f;
#pragma unroll
        for (int w = 0; w < 8; ++w) s += red[w];
        atomicAdd(&loss[img], s);
        unsigned done = __hip_atomic_fetch_add(ws_u32 + 4, 1u,
                                               __ATOMIC_ACQ_REL, AGENT);
        if (done == (unsigned)(NIMG*NBAND - 1)) {
            float tot = 0.f;
#pragma unroll
            for (int i = 0; i < 4; ++i)
                tot += __hip_atomic_load(ws_f + i, __ATOMIC_RELAXED, AGENT);
            out[0] = tot;
            out[1] = tot;
            out[2] = 0.f;
        }
    }
}

// ---- fallback (ws too small): R1-verified single-kernel path ----
__global__ __launch_bounds__(1024) void ot_fallback_kernel(
    const float* __restrict__ dens, const float* __restrict__ pts,
    float* __restrict__ out)
{
    const int img = blockIdx.x, t = threadIdx.x;
    __shared__ float sv[NCELL];
    __shared__ float redf[16];

    const float px = pts[(size_t)img*NPTS*2 + t*2 + 0];
    const float py = pts[(size_t)img*NPTS*2 + t*2 + 1];
    int r_lo, c_lo; window_of(px, py, r_lo, c_lo);

    float dx2[WIN], dy2[WIN];
#pragma unroll
    for (int j = 0; j < WIN; ++j) {
        float dx = px - (float)(8*(c_lo+j) + 4);
        float dy = py - (float)(8*(r_lo+j) + 4);
        dx2[j] = dx*dx; dy2[j] = dy*dy;
    }
    float K[WIN*WIN];
#pragma unroll
    for (int wy = 0; wy < WIN; ++wy)
#pragma unroll
        for (int wx = 0; wx < WIN; ++wx)
            K[wy*WIN+wx] = exp2f(C2 * (dx2[wx] + dy2[wy]));

    const int lbase = r_lo*GRID_N + c_lo;
    float breg[16];
    const float4* d4 = (const float4*)(dens + (size_t)img*NCELL + t*16);
#pragma unroll
    for (int j = 0; j < 4; ++j) {
        float4 v = d4[j];
        breg[j*4+0]=v.x; breg[j*4+1]=v.y; breg[j*4+2]=v.z; breg[j*4+3]=v.w;
    }
    const float A = 1.0f/(float)NPTS;
    float u = A;
    float4* sv4 = (float4*)sv;
    for (int it = 0; it < NITER; ++it) {
        __syncthreads();
#pragma unroll
        for (int j = 0; j < 4; ++j) sv4[t*4+j] = make_float4(0.f,0.f,0.f,0.f);
        __syncthreads();
#pragma unroll
        for (int wy = 0; wy < WIN; ++wy)
#pragma unroll
            for (int wx = 0; wx < WIN; ++wx)
                atomicAdd(&sv[lbase + wy*GRID_N + wx], u * K[wy*WIN+wx]);
        __syncthreads();
#pragma unroll
        for (int j = 0; j < 16; ++j) { int c = t*16+j; sv[c] = breg[j] / (sv[c] + EPSF); }
        __syncthreads();
        float kv = 0.f;
#pragma unroll
        for (int wy = 0; wy < WIN; ++wy)
#pragma unroll
            for (int wx = 0; wx < WIN; ++wx)
                kv = fmaf(K[wy*WIN+wx], sv[lbase + wy*GRID_N + wx], kv);
        u = A / (kv + EPSF);
    }
    float li = 0.f;
#pragma unroll
    for (int wy = 0; wy < WIN; ++wy)
#pragma unroll
        for (int wx = 0; wx < WIN; ++wx)
            li = fmaf(K[wy*WIN+wx] * (dx2[wx]+dy2[wy]), sv[lbase + wy*GRID_N + wx], li);
    li *= u;
#pragma unroll
    for (int o = 32; o > 0; o >>= 1) li += __shfl_down(li, o);
    if ((t & 63) == 0) redf[t >> 6] = li;
    __syncthreads();
    if (t == 0) {
        float s = 0.f;
#pragma unroll
        for (int w = 0; w < 16; ++w) s += redf[w];
        atomicAdd(&out[0], s);
        atomicAdd(&out[1], s);
    }
}

extern "C" void kernel_launch(void* const* d_in, const int* in_sizes, int n_in,
                              void* d_out, int out_size, void* d_ws, size_t ws_size,
                              hipStream_t stream)
{
    const float* dens = (const float*)d_in[0];   // [4,1,128,128]
    const float* pts  = (const float*)d_in[2];   // [4,1024,2]
    float* out = (float*)d_out;
    unsigned* ws_u32 = (unsigned*)d_ws;

    if (ws_size < (size_t)WS_TOTAL) {   // insurance: slow-but-correct path
        hipMemsetAsync(d_out, 0, 3*sizeof(float), stream);
        ot_fallback_kernel<<<NIMG, 1024, 0, stream>>>(dens, pts, out);
        return;
    }

    hipMemsetAsync(d_ws, 0, ZERO_BYTES, stream);   // loss + done + flags
    ot_setup_kernel<<<NIMG, 1024, 0, stream>>>(pts, ws_u32);
    ot_main_kernel <<<NIMG*NBAND, TPB, 0, stream>>>(dens, pts, ws_u32, out);
}

// Round 8
// 796.161 us; speedup vs baseline: 6121.9494x; 1.1117x over previous
//
#include <hip/hip_runtime.h>

// OT Sinkhorn loss. B=4 images, N=1024 pts, 128x128 grid, 100 iters.
// R8: stamped-u sync. u published as 64-bit {stamp=it+1 | u_bits} into
// parity-double-buffered u2[2][1024]; consumers poll the word itself
// (monotone >= -- CANNOT deadlock, unlike R6's equality poll) -> detect +
// load = ONE LLC access, no flags, no fences. Double buffer makes it
// strict: buffer (it-1)&1 can't hold stamp it+1 until producer has OUR
// u^it, which we haven't published while staging. Plus 3-barrier shfl
// scan in setup (was 20 barriers).
// R7 was 637us main: ~3 serialized LLC round trips per iter (store drain,
// flag RT, staged loads); LDS entry cache + flag sync proven there.

#define GRID_N 128
#define NCELL  16384
#define NPTS   1024
#define NIMG   4
#define WIN    7
#define WHALF  3
#define NITER  100
#define NBAND  16
#define TPB    512
#define VROWS  14
#define HCELLS (VROWS*GRID_N)   // 1792
#define EPI    (NPTS*49)        // 50176
#define ENT_CAP 10240           // LDS entry cache (expected ~5500/band)

#define C2   (-0.14426950408889634f)   // -log2(e)/10
#define EPSF 1e-16f

// ws layout (bytes)
#define WS_LOSS_B   0         // f32[4] + u32 done-counter @16
#define WS_U_B      64        // u64[4][2][1024] stamped u (parity buffers)
#define WS_BOFS_B   65600     // u32[4][32] (17 used)
#define WS_PLIST_B  66112     // u32[4][1024] band-sorted pids
#define WS_COUNTS_B 82496     // u32[4][16384]
#define WS_OFFS_B   344640    // u32[4][16400]
#define OFF_STRIDE  16400
#define WS_ENTC_B   607040    // u32[4][50176] {K22|pid10} cell-major CSR
#define WS_TOTAL    1409856
#define ZERO_BYTES  65600     // loss + done-counter + stamped-u buffers

#define AGENT __HIP_MEMORY_SCOPE_AGENT

__device__ __forceinline__ void window_of(float px, float py, int& r_lo, int& c_lo)
{
    int kc = (int)(px * 0.125f); kc = kc < 0 ? 0 : (kc > GRID_N-1 ? GRID_N-1 : kc);
    int kr = (int)(py * 0.125f); kr = kr < 0 ? 0 : (kr > GRID_N-1 ? GRID_N-1 : kr);
    c_lo = kc - WHALF; c_lo = c_lo < 0 ? 0 : (c_lo > GRID_N-WIN ? GRID_N-WIN : c_lo);
    r_lo = kr - WHALF; r_lo = r_lo < 0 ? 0 : (r_lo > GRID_N-WIN ? GRID_N-WIN : r_lo);
}

// ---- fused setup: zero counts -> count -> scan -> fill -> psort ----
__global__ __launch_bounds__(1024) void ot_setup_kernel(
    const float* __restrict__ pts, unsigned* __restrict__ ws_u32)
{
    const int img = blockIdx.x, t = threadIdx.x;
    unsigned* counts = ws_u32 + WS_COUNTS_B/4 + img*NCELL;
    unsigned* offs   = ws_u32 + WS_OFFS_B/4 + img*OFF_STRIDE;
    unsigned* entC   = ws_u32 + WS_ENTC_B/4 + img*EPI;

    __shared__ unsigned sc[16];
    __shared__ unsigned cnt[16];
    __shared__ unsigned pos[17];

    // phase 0: zero counts
    {
        uint4 z = make_uint4(0,0,0,0);
        uint4* w4 = (uint4*)(counts + t*16);
#pragma unroll
        for (int j = 0; j < 4; ++j) w4[j] = z;
    }
    __syncthreads();

    // phase 1: count points covering each cell
    const float px = pts[(img*NPTS + t)*2 + 0];
    const float py = pts[(img*NPTS + t)*2 + 1];
    int r_lo, c_lo; window_of(px, py, r_lo, c_lo);
#pragma unroll
    for (int wy = 0; wy < WIN; ++wy)
#pragma unroll
        for (int wx = 0; wx < WIN; ++wx)
            atomicAdd(&counts[(r_lo+wy)*GRID_N + c_lo + wx], 1u);
    __syncthreads();

    // phase 2: exclusive scan counts -> offs (3-level shfl scan, 2 barriers)
    {
        unsigned c[16];
        const uint4* c4 = (const uint4*)(counts + t*16);
#pragma unroll
        for (int j = 0; j < 4; ++j) {
            uint4 v = c4[j];
            c[j*4+0]=v.x; c[j*4+1]=v.y; c[j*4+2]=v.z; c[j*4+3]=v.w;
        }
        unsigned s = 0;
#pragma unroll
        for (int k = 0; k < 16; ++k) s += c[k];

        const int lane = t & 63;
        unsigned inc = s;
#pragma unroll
        for (int d = 1; d < 64; d <<= 1) {
            unsigned x = __shfl_up(inc, d, 64);
            if (lane >= d) inc += x;
        }
        if (lane == 63) sc[t >> 6] = inc;     // wave totals
        __syncthreads();
        if (t < 16) {
            unsigned wv = sc[t];
            unsigned winc = wv;
#pragma unroll
            for (int d = 1; d < 16; d <<= 1) {
                unsigned x = __shfl_up(winc, d, 16);
                if (t >= d) winc += x;
            }
            sc[t] = winc - wv;                // exclusive wave offset
        }
        __syncthreads();
        unsigned run = sc[t >> 6] + inc - s;  // exclusive prefix
#pragma unroll
        for (int k = 0; k < 16; ++k) { offs[t*16+k] = run; run += c[k]; }
        if (t == 1023) offs[NCELL] = run;     // = 50176
    }
    __syncthreads();

    // phase 3: fill cell-major entries {K22|pid10}; drains counts
#pragma unroll
    for (int wy = 0; wy < WIN; ++wy) {
        float dy = py - (float)(8*(r_lo+wy) + 4);
#pragma unroll
        for (int wx = 0; wx < WIN; ++wx) {
            float dx = px - (float)(8*(c_lo+wx) + 4);
            float K = exp2f(C2 * (dx*dx + dy*dy));
            unsigned Kb = __float_as_uint(K);
            unsigned e = ((Kb + 0x200u) & 0xFFFFFC00u) | (unsigned)t;
            int cell = (r_lo+wy)*GRID_N + c_lo + wx;
            unsigned old = atomicSub(&counts[cell], 1u);
            entC[offs[cell] + old - 1u] = e;
        }
    }
    __syncthreads();

    // phase 4: counting-sort by band
    if (t < 16) cnt[t] = 0;
    __syncthreads();
    int kr = (int)(py * 0.125f); kr = kr < 0 ? 0 : (kr > 127 ? 127 : kr);
    int b = kr >> 3;
    atomicAdd(&cnt[b], 1u);
    __syncthreads();
    if (t == 0) {
        unsigned run = 0;
        for (int i = 0; i < 16; ++i) { pos[i] = run; run += cnt[i]; }
        pos[16] = run;
    }
    __syncthreads();
    unsigned* bofs = ws_u32 + WS_BOFS_B/4 + img*32;
    if (t < 17) bofs[t] = pos[t];
    __syncthreads();
    unsigned slot = atomicAdd(&pos[b], 1u);
    ws_u32[WS_PLIST_B/4 + img*NPTS + slot] = (unsigned)t;
}

// ---- poll stamped u: wait stamp >= target (MONOTONE), return value ----
__device__ __forceinline__ float poll_u2(const unsigned long long* addr, unsigned target)
{
    unsigned long long w = __hip_atomic_load(addr, __ATOMIC_RELAXED, AGENT);
    int spins = 0;
    while ((unsigned)(w >> 32) < target) {
        __builtin_amdgcn_s_sleep(1);
        w = __hip_atomic_load(addr, __ATOMIC_RELAXED, AGENT);
        if (++spins > (1<<22)) break;   // safety net; monotone => unreachable
    }
    return __uint_as_float((unsigned)w);
}

// ---- main: 64 WGs (4 img x 16 bands); LDS entries + stamped-u sync ----
__global__ __launch_bounds__(TPB) void ot_main_kernel(
    const float* __restrict__ dens, const float* __restrict__ pts,
    unsigned* __restrict__ ws_u32, float* __restrict__ out)
{
    const int img = (int)blockIdx.x >> 4, bnd = (int)blockIdx.x & 15;
    const int t = threadIdx.x;
    float* ws_f = (float*)ws_u32;

    float* loss = ws_f;
    unsigned long long* u2_g =
        (unsigned long long*)((char*)ws_u32 + WS_U_B) + img*2*NPTS;
    const unsigned* bofs  = ws_u32 + WS_BOFS_B/4 + img*32;
    const unsigned* plist = ws_u32 + WS_PLIST_B/4 + img*NPTS;
    const unsigned* offs  = ws_u32 + WS_OFFS_B/4 + img*OFF_STRIDE;
    const unsigned* entC  = ws_u32 + WS_ENTC_B/4 + img*EPI;

    __shared__ float    u_lds[NPTS];
    __shared__ float    v_loc[HCELLS];    // rows (8*bnd-3)..(8*bnd+10)
    __shared__ unsigned ent_l[ENT_CAP];
    __shared__ float    red[8];

    const int rowbase = bnd*8 - 3;
    const int row0 = rowbase < 0 ? 0 : rowbase;
    const int row1 = (rowbase + VROWS) > GRID_N ? GRID_N : (rowbase + VROWS);
    const unsigned e0 = offs[row0*GRID_N];
    const unsigned e1 = offs[row1*GRID_N];
    const int n_ent = (int)(e1 - e0);

    // copy constant entry stream into LDS (contiguous CSR range)
    for (int i = t; i < n_ent && i < ENT_CAP; i += TPB) ent_l[i] = entC[e0 + i];

    // ---- static cell side: up to 4 halo cells/thread (stride TPB) ----
    int cofs[4], ccnt[4], cvi[4]; float cb[4];
#pragma unroll
    for (int k = 0; k < 4; ++k) {
        int hc = t + k*TPB;            // 0..2047; valid < 1792
        ccnt[k] = 0; cvi[k] = 0; cb[k] = 0.f; cofs[k] = 0;
        if (hc < HCELLS) {
            int grow = rowbase + (hc >> 7);
            if (grow >= 0 && grow < GRID_N) {
                int gc = grow*GRID_N + (hc & 127);
                unsigned oA = offs[gc], oB = offs[gc+1];
                cofs[k] = (int)(oA - e0); ccnt[k] = (int)(oB - oA);
                cb[k] = dens[img*NCELL + gc];
                cvi[k] = hc;
            }
        }
    }

    // ---- static point side: 4 threads/point ----
    const int p0 = (int)bofs[bnd], p1 = (int)bofs[bnd+1];
    const int npts = p1 - p0;
    const int sub = t & 3;
    const int idx = t >> 2;
    int mypid = -1, km = 0;
    float Kq[13], Kd2[13];
    int   cq[13];
    if (idx < npts && idx < 128) {
        mypid = (int)plist[p0 + idx];
        float px = pts[(img*NPTS + mypid)*2 + 0];
        float py = pts[(img*NPTS + mypid)*2 + 1];
        int r_lo, c_lo; window_of(px, py, r_lo, c_lo);
        int k = 0;
#pragma unroll
        for (int q = 0; q < 49; ++q) {
            if ((q & 3) == sub) {
                int wy = q / 7, wx = q % 7;
                float dx = px - (float)(8*(c_lo+wx) + 4);
                float dy = py - (float)(8*(r_lo+wy) + 4);
                float d2 = dx*dx + dy*dy;
                float K = exp2f(C2 * d2);
                Kq[k] = K; Kd2[k] = K * d2;
                cq[k] = (r_lo + wy - rowbase)*GRID_N + (c_lo + wx);
                ++k;
            }
        }
        km = k;   // 13 or 12
    }
    const int lo = (int)bofs[bnd > 0 ? bnd-1 : 0];
    const int hi = (int)bofs[bnd < 15 ? bnd+2 : 16];
    const float A = 1.0f / (float)NPTS;

    u_lds[t] = A; u_lds[t + TPB] = A;
    float li_acc = 0.f;

    for (int it = 0; it < NITER; ++it) {
        if (it > 0) {
            // stage neighbor u^{it-1}: poll stamped word, parity (it-1)&1
            const unsigned long long* src = u2_g + (unsigned)((it-1) & 1)*NPTS;
            const unsigned tgt = (unsigned)it;      // stamp = src_iter+1
            for (int i = lo + t; i < p0; i += TPB) {
                unsigned pid = plist[i];
                u_lds[pid] = poll_u2(src + pid, tgt);
            }
            for (int i = p1 + t; i < hi; i += TPB) {
                unsigned pid = plist[i];
                u_lds[pid] = poll_u2(src + pid, tgt);
            }
        }
        __syncthreads();

        // ---- phase A (redundant halo, pure LDS): v = b/(K^T u + eps) ----
#pragma unroll
        for (int k = 0; k < 4; ++k) {
            int cn = ccnt[k];
            if (cn > 0) {
                float s = 0.f;
                int le = cofs[k];
                if (le + cn <= ENT_CAP) {
                    for (int e = 0; e < cn; ++e) {
                        unsigned E = ent_l[le + e];
                        s = fmaf(__uint_as_float(E & 0xFFFFFC00u), u_lds[E & 0x3FFu], s);
                    }
                } else {
                    for (int e = 0; e < cn; ++e) {   // overflow: L2 path
                        unsigned E = entC[e0 + le + e];
                        s = fmaf(__uint_as_float(E & 0xFFFFFC00u), u_lds[E & 0x3FFu], s);
                    }
                }
                v_loc[cvi[k]] = cb[k] / (s + EPSF);
            }
        }
        __syncthreads();

        // ---- phase B: u = A/(K v + eps); publish stamped u ----
        unsigned long long* dst = u2_g + (unsigned)(it & 1)*NPTS;
        const unsigned long long hi_stamp = ((unsigned long long)(unsigned)(it+1)) << 32;
        if (mypid >= 0) {
            float kv = 0.f, kd = 0.f;
#pragma unroll
            for (int k = 0; k < 13; ++k) {
                if (k < km) {
                    float vj = v_loc[cq[k]];
                    kv = fmaf(Kq[k],  vj, kv);
                    kd = fmaf(Kd2[k], vj, kd);
                }
            }
            kv += __shfl_xor(kv, 1); kv += __shfl_xor(kv, 2);
            float u_new = A / (kv + EPSF);
            if (sub == 0) {
                u_lds[mypid] = u_new;
                __hip_atomic_store(dst + mypid,
                                   hi_stamp | __float_as_uint(u_new),
                                   __ATOMIC_RELAXED, AGENT);
            }
            if (it == NITER-1) {
                kd += __shfl_xor(kd, 1); kd += __shfl_xor(kd, 2);
                if (sub == 0) li_acc += u_new * kd;
            }
        }
        // rare overflow (band with >128 points): compute K inline
        for (int base2 = 128; base2 < npts; base2 += 128) {
            int idx2 = base2 + idx;
            if (idx2 < npts) {
                int pid2 = (int)plist[p0 + idx2];
                float px = pts[(img*NPTS + pid2)*2 + 0];
                float py = pts[(img*NPTS + pid2)*2 + 1];
                int r_lo, c_lo; window_of(px, py, r_lo, c_lo);
                float kv = 0.f, kd = 0.f;
                for (int q = sub; q < 49; q += 4) {
                    int wy = q / 7, wx = q % 7;
                    float dx = px - (float)(8*(c_lo+wx) + 4);
                    float dy = py - (float)(8*(r_lo+wy) + 4);
                    float d2 = dx*dx + dy*dy;
                    float K = exp2f(C2 * d2);
                    float vj = v_loc[(r_lo + wy - rowbase)*GRID_N + c_lo + wx];
                    kv = fmaf(K, vj, kv); kd = fmaf(K*d2, vj, kd);
                }
                kv += __shfl_xor(kv, 1); kv += __shfl_xor(kv, 2);
                float u_new = A / (kv + EPSF);
                if (sub == 0) {
                    u_lds[pid2] = u_new;
                    __hip_atomic_store(dst + pid2,
                                       hi_stamp | __float_as_uint(u_new),
                                       __ATOMIC_RELAXED, AGENT);
                }
                if (it == NITER-1) {
                    kd += __shfl_xor(kd, 1); kd += __shfl_xor(kd, 2);
                    if (sub == 0) li_acc += u_new * kd;
                }
            }
        }
        __syncthreads();   // u_lds[own] final before next staging writes
    }

    // ---- loss reduction + last-WG finalize ----
#pragma unroll
    for (int o = 32; o > 0; o >>= 1) li_acc += __shfl_down(li_acc, o);
    if ((t & 63) == 0) red[t >> 6] = li_acc;
    __syncthreads();
    if (t == 0) {
        float s = 0.f;
#pragma unroll
        for (int w = 0; w < 8; ++w) s += red[w];
        atomicAdd(&loss[img], s);
        unsigned done = __hip_atomic_fetch_add(ws_u32 + 4, 1u,
                                               __ATOMIC_ACQ_REL, AGENT);
        if (done == (unsigned)(NIMG*NBAND - 1)) {
            float tot = 0.f;
#pragma unroll
            for (int i = 0; i < 4; ++i)
                tot += __hip_atomic_load(ws_f + i, __ATOMIC_RELAXED, AGENT);
            out[0] = tot;
            out[1] = tot;
            out[2] = 0.f;
        }
    }
}

// ---- fallback (ws too small): R1-verified single-kernel path ----
__global__ __launch_bounds__(1024) void ot_fallback_kernel(
    const float* __restrict__ dens, const float* __restrict__ pts,
    float* __restrict__ out)
{
    const int img = blockIdx.x, t = threadIdx.x;
    __shared__ float sv[NCELL];
    __shared__ float redf[16];

    const float px = pts[(size_t)img*NPTS*2 + t*2 + 0];
    const float py = pts[(size_t)img*NPTS*2 + t*2 + 1];
    int r_lo, c_lo; window_of(px, py, r_lo, c_lo);

    float dx2[WIN], dy2[WIN];
#pragma unroll
    for (int j = 0; j < WIN; ++j) {
        float dx = px - (float)(8*(c_lo+j) + 4);
        float dy = py - (float)(8*(r_lo+j) + 4);
        dx2[j] = dx*dx; dy2[j] = dy*dy;
    }
    float K[WIN*WIN];
#pragma unroll
    for (int wy = 0; wy < WIN; ++wy)
#pragma unroll
        for (int wx = 0; wx < WIN; ++wx)
            K[wy*WIN+wx] = exp2f(C2 * (dx2[wx] + dy2[wy]));

    const int lbase = r_lo*GRID_N + c_lo;
    float breg[16];
    const float4* d4 = (const float4*)(dens + (size_t)img*NCELL + t*16);
#pragma unroll
    for (int j = 0; j < 4; ++j) {
        float4 v = d4[j];
        breg[j*4+0]=v.x; breg[j*4+1]=v.y; breg[j*4+2]=v.z; breg[j*4+3]=v.w;
    }
    const float A = 1.0f/(float)NPTS;
    float u = A;
    float4* sv4 = (float4*)sv;
    for (int it = 0; it < NITER; ++it) {
        __syncthreads();
#pragma unroll
        for (int j = 0; j < 4; ++j) sv4[t*4+j] = make_float4(0.f,0.f,0.f,0.f);
        __syncthreads();
#pragma unroll
        for (int wy = 0; wy < WIN; ++wy)
#pragma unroll
            for (int wx = 0; wx < WIN; ++wx)
                atomicAdd(&sv[lbase + wy*GRID_N + wx], u * K[wy*WIN+wx]);
        __syncthreads();
#pragma unroll
        for (int j = 0; j < 16; ++j) { int c = t*16+j; sv[c] = breg[j] / (sv[c] + EPSF); }
        __syncthreads();
        float kv = 0.f;
#pragma unroll
        for (int wy = 0; wy < WIN; ++wy)
#pragma unroll
            for (int wx = 0; wx < WIN; ++wx)
                kv = fmaf(K[wy*WIN+wx], sv[lbase + wy*GRID_N + wx], kv);
        u = A / (kv + EPSF);
    }
    float li = 0.f;
#pragma unroll
    for (int wy = 0; wy < WIN; ++wy)
#pragma unroll
        for (int wx = 0; wx < WIN; ++wx)
            li = fmaf(K[wy*WIN+wx] * (dx2[wx]+dy2[wy]), sv[lbase + wy*GRID_N + wx], li);
    li *= u;
#pragma unroll
    for (int o = 32; o > 0; o >>= 1) li += __shfl_down(li, o);
    if ((t & 63) == 0) redf[t >> 6] = li;
    __syncthreads();
    if (t == 0) {
        float s = 0.f;
#pragma unroll
        for (int w = 0; w < 16; ++w) s += redf[w];
        atomicAdd(&out[0], s);
        atomicAdd(&out[1], s);
    }
}

extern "C" void kernel_launch(void* const* d_in, const int* in_sizes, int n_in,
                              void* d_out, int out_size, void* d_ws, size_t ws_size,
                              hipStream_t stream)
{
    const float* dens = (const float*)d_in[0];   // [4,1,128,128]
    const float* pts  = (const float*)d_in[2];   // [4,1024,2]
    float* out = (float*)d_out;
    unsigned* ws_u32 = (unsigned*)d_ws;

    if (ws_size < (size_t)WS_TOTAL) {   // insurance: slow-but-correct path
        hipMemsetAsync(d_out, 0, 3*sizeof(float), stream);
        ot_fallback_kernel<<<NIMG, 1024, 0, stream>>>(dens, pts, out);
        return;
    }

    hipMemsetAsync(d_ws, 0, ZERO_BYTES, stream);   // loss + done + stamps
    ot_setup_kernel<<<NIMG, 1024, 0, stream>>>(pts, ws_u32);
    ot_main_kernel <<<NIMG*NBAND, TPB, 0, stream>>>(dens, pts, ws_u32, out);
}

// Round 9
// 760.694 us; speedup vs baseline: 6407.3816x; 1.0466x over previous
//
#include <hip/hip_runtime.h>

// OT Sinkhorn loss. B=4 images, N=1024 pts, 128x128 grid, 100 iters.
// R9: u2 indexed by SORTED POSITION (band-contiguous), not pid. Band's
// publishes = 8 coherent lines (was ~64 random); neighbor polls = 8 lines
// (was ~100) -- attacks the measured 4.4us/iter publish->detect residue.
// Sync = R8's stamped monotone poll + parity double buffer (proven).
// R8 was 541us main, FETCH 34MB (poll-retry refetch of scattered lines).

#define GRID_N 128
#define NCELL  16384
#define NPTS   1024
#define NIMG   4
#define WIN    7
#define WHALF  3
#define NITER  100
#define NBAND  16
#define TPB    512
#define VROWS  14
#define HCELLS (VROWS*GRID_N)   // 1792
#define EPI    (NPTS*49)        // 50176
#define ENT_CAP 10240           // LDS entry cache (expected ~5500/band)

#define C2   (-0.14426950408889634f)   // -log2(e)/10
#define EPSF 1e-16f

// ws layout (bytes)
#define WS_LOSS_B   0         // f32[4] + u32 done-counter @16
#define WS_U_B      64        // u64[4][2][1024] stamped u, POSITION-indexed
#define WS_BOFS_B   65600     // u32[4][32] (17 used)
#define WS_PLIST_B  66112     // u32[4][1024] pos -> pid
#define WS_COUNTS_B 82496     // u32[4][16384]
#define WS_OFFS_B   344640    // u32[4][16400]
#define OFF_STRIDE  16400
#define WS_ENTC_B   607040    // u32[4][50176] {K22|pos10} cell-major CSR
#define WS_TOTAL    1409856
#define ZERO_BYTES  65600     // loss + done-counter + stamped-u buffers

#define AGENT __HIP_MEMORY_SCOPE_AGENT

__device__ __forceinline__ void window_of(float px, float py, int& r_lo, int& c_lo)
{
    int kc = (int)(px * 0.125f); kc = kc < 0 ? 0 : (kc > GRID_N-1 ? GRID_N-1 : kc);
    int kr = (int)(py * 0.125f); kr = kr < 0 ? 0 : (kr > GRID_N-1 ? GRID_N-1 : kr);
    c_lo = kc - WHALF; c_lo = c_lo < 0 ? 0 : (c_lo > GRID_N-WIN ? GRID_N-WIN : c_lo);
    r_lo = kr - WHALF; r_lo = r_lo < 0 ? 0 : (r_lo > GRID_N-WIN ? GRID_N-WIN : r_lo);
}

// ---- fused setup: zero -> psort -> count -> scan -> fill(pos) ----
__global__ __launch_bounds__(1024) void ot_setup_kernel(
    const float* __restrict__ pts, unsigned* __restrict__ ws_u32)
{
    const int img = blockIdx.x, t = threadIdx.x;
    unsigned* counts = ws_u32 + WS_COUNTS_B/4 + img*NCELL;
    unsigned* offs   = ws_u32 + WS_OFFS_B/4 + img*OFF_STRIDE;
    unsigned* entC   = ws_u32 + WS_ENTC_B/4 + img*EPI;

    __shared__ unsigned sc[16];
    __shared__ unsigned cnt[16];
    __shared__ unsigned pos[17];

    // phase 0: zero counts + band histogram
    {
        uint4 z = make_uint4(0,0,0,0);
        uint4* w4 = (uint4*)(counts + t*16);
#pragma unroll
        for (int j = 0; j < 4; ++j) w4[j] = z;
    }
    if (t < 16) cnt[t] = 0;
    __syncthreads();

    // phase 1: counting-sort by band -> my sorted position (slot)
    const float px = pts[(img*NPTS + t)*2 + 0];
    const float py = pts[(img*NPTS + t)*2 + 1];
    int kr = (int)(py * 0.125f); kr = kr < 0 ? 0 : (kr > 127 ? 127 : kr);
    const int band = kr >> 3;
    atomicAdd(&cnt[band], 1u);
    __syncthreads();
    if (t == 0) {
        unsigned run = 0;
        for (int i = 0; i < 16; ++i) { pos[i] = run; run += cnt[i]; }
        pos[16] = run;
    }
    __syncthreads();
    unsigned* bofs = ws_u32 + WS_BOFS_B/4 + img*32;
    if (t < 17) bofs[t] = pos[t];
    __syncthreads();
    const unsigned slot = atomicAdd(&pos[band], 1u);
    ws_u32[WS_PLIST_B/4 + img*NPTS + slot] = (unsigned)t;
    __syncthreads();

    // phase 2: count points covering each cell
    int r_lo, c_lo; window_of(px, py, r_lo, c_lo);
#pragma unroll
    for (int wy = 0; wy < WIN; ++wy)
#pragma unroll
        for (int wx = 0; wx < WIN; ++wx)
            atomicAdd(&counts[(r_lo+wy)*GRID_N + c_lo + wx], 1u);
    __syncthreads();

    // phase 3: exclusive scan counts -> offs (shfl, 2 barriers)
    {
        unsigned c[16];
        const uint4* c4 = (const uint4*)(counts + t*16);
#pragma unroll
        for (int j = 0; j < 4; ++j) {
            uint4 v = c4[j];
            c[j*4+0]=v.x; c[j*4+1]=v.y; c[j*4+2]=v.z; c[j*4+3]=v.w;
        }
        unsigned s = 0;
#pragma unroll
        for (int k = 0; k < 16; ++k) s += c[k];

        const int lane = t & 63;
        unsigned inc = s;
#pragma unroll
        for (int d = 1; d < 64; d <<= 1) {
            unsigned x = __shfl_up(inc, d, 64);
            if (lane >= d) inc += x;
        }
        if (lane == 63) sc[t >> 6] = inc;     // wave totals
        __syncthreads();
        if (t < 16) {
            unsigned wv = sc[t];
            unsigned winc = wv;
#pragma unroll
            for (int d = 1; d < 16; d <<= 1) {
                unsigned x = __shfl_up(winc, d, 16);
                if (t >= d) winc += x;
            }
            sc[t] = winc - wv;                // exclusive wave offset
        }
        __syncthreads();
        unsigned run = sc[t >> 6] + inc - s;  // exclusive prefix
#pragma unroll
        for (int k = 0; k < 16; ++k) { offs[t*16+k] = run; run += c[k]; }
        if (t == 1023) offs[NCELL] = run;     // = 50176
    }
    __syncthreads();

    // phase 4: fill cell-major entries {K22 | slot10}; drains counts
#pragma unroll
    for (int wy = 0; wy < WIN; ++wy) {
        float dy = py - (float)(8*(r_lo+wy) + 4);
#pragma unroll
        for (int wx = 0; wx < WIN; ++wx) {
            float dx = px - (float)(8*(c_lo+wx) + 4);
            float K = exp2f(C2 * (dx*dx + dy*dy));
            unsigned Kb = __float_as_uint(K);
            unsigned e = ((Kb + 0x200u) & 0xFFFFFC00u) | slot;
            int cell = (r_lo+wy)*GRID_N + c_lo + wx;
            unsigned old = atomicSub(&counts[cell], 1u);
            entC[offs[cell] + old - 1u] = e;
        }
    }
}

// ---- poll stamped u: wait stamp >= target (MONOTONE), return value ----
__device__ __forceinline__ float poll_u2(const unsigned long long* addr, unsigned target)
{
    unsigned long long w = __hip_atomic_load(addr, __ATOMIC_RELAXED, AGENT);
    int spins = 0;
    while ((unsigned)(w >> 32) < target) {
        __builtin_amdgcn_s_sleep(1);
        w = __hip_atomic_load(addr, __ATOMIC_RELAXED, AGENT);
        if (++spins > (1<<22)) break;   // safety net; monotone => unreachable
    }
    return __uint_as_float((unsigned)w);
}

// ---- main: 64 WGs (4 img x 16 bands); position-indexed stamped-u sync ----
__global__ __launch_bounds__(TPB) void ot_main_kernel(
    const float* __restrict__ dens, const float* __restrict__ pts,
    unsigned* __restrict__ ws_u32, float* __restrict__ out)
{
    const int img = (int)blockIdx.x >> 4, bnd = (int)blockIdx.x & 15;
    const int t = threadIdx.x;
    float* ws_f = (float*)ws_u32;

    float* loss = ws_f;
    unsigned long long* u2_g =
        (unsigned long long*)((char*)ws_u32 + WS_U_B) + img*2*NPTS;
    const unsigned* bofs  = ws_u32 + WS_BOFS_B/4 + img*32;
    const unsigned* plist = ws_u32 + WS_PLIST_B/4 + img*NPTS;
    const unsigned* offs  = ws_u32 + WS_OFFS_B/4 + img*OFF_STRIDE;
    const unsigned* entC  = ws_u32 + WS_ENTC_B/4 + img*EPI;

    __shared__ float    u_lds[NPTS];      // indexed by sorted position
    __shared__ float    v_loc[HCELLS];    // rows (8*bnd-3)..(8*bnd+10)
    __shared__ unsigned ent_l[ENT_CAP];
    __shared__ float    red[8];

    const int rowbase = bnd*8 - 3;
    const int row0 = rowbase < 0 ? 0 : rowbase;
    const int row1 = (rowbase + VROWS) > GRID_N ? GRID_N : (rowbase + VROWS);
    const unsigned e0 = offs[row0*GRID_N];
    const unsigned e1 = offs[row1*GRID_N];
    const int n_ent = (int)(e1 - e0);

    // copy constant entry stream into LDS (contiguous CSR range)
    for (int i = t; i < n_ent && i < ENT_CAP; i += TPB) ent_l[i] = entC[e0 + i];

    // ---- static cell side: up to 4 halo cells/thread (stride TPB) ----
    int cofs[4], ccnt[4], cvi[4]; float cb[4];
#pragma unroll
    for (int k = 0; k < 4; ++k) {
        int hc = t + k*TPB;            // 0..2047; valid < 1792
        ccnt[k] = 0; cvi[k] = 0; cb[k] = 0.f; cofs[k] = 0;
        if (hc < HCELLS) {
            int grow = rowbase + (hc >> 7);
            if (grow >= 0 && grow < GRID_N) {
                int gc = grow*GRID_N + (hc & 127);
                unsigned oA = offs[gc], oB = offs[gc+1];
                cofs[k] = (int)(oA - e0); ccnt[k] = (int)(oB - oA);
                cb[k] = dens[img*NCELL + gc];
                cvi[k] = hc;
            }
        }
    }

    // ---- static point side: 4 threads/point, position-indexed ----
    const int p0 = (int)bofs[bnd], p1 = (int)bofs[bnd+1];
    const int npts = p1 - p0;
    const int sub = t & 3;
    const int idx = t >> 2;
    int mypos = -1, km = 0;
    float Kq[13], Kd2[13];
    int   cq[13];
    if (idx < npts && idx < 128) {
        mypos = p0 + idx;
        int pid = (int)plist[mypos];
        float px = pts[(img*NPTS + pid)*2 + 0];
        float py = pts[(img*NPTS + pid)*2 + 1];
        int r_lo, c_lo; window_of(px, py, r_lo, c_lo);
        int k = 0;
#pragma unroll
        for (int q = 0; q < 49; ++q) {
            if ((q & 3) == sub) {
                int wy = q / 7, wx = q % 7;
                float dx = px - (float)(8*(c_lo+wx) + 4);
                float dy = py - (float)(8*(r_lo+wy) + 4);
                float d2 = dx*dx + dy*dy;
                float K = exp2f(C2 * d2);
                Kq[k] = K; Kd2[k] = K * d2;
                cq[k] = (r_lo + wy - rowbase)*GRID_N + (c_lo + wx);
                ++k;
            }
        }
        km = k;   // 13 or 12
    }
    const int lo = (int)bofs[bnd > 0 ? bnd-1 : 0];
    const int hi = (int)bofs[bnd < 15 ? bnd+2 : 16];
    const float A = 1.0f / (float)NPTS;

    u_lds[t] = A; u_lds[t + TPB] = A;
    float li_acc = 0.f;

    for (int it = 0; it < NITER; ++it) {
        if (it > 0) {
            // stage neighbor u^{it-1}: contiguous position ranges, parity buf
            const unsigned long long* src = u2_g + (unsigned)((it-1) & 1)*NPTS;
            const unsigned tgt = (unsigned)it;      // stamp = src_iter+1
            for (int i = lo + t; i < p0; i += TPB)
                u_lds[i] = poll_u2(src + i, tgt);
            for (int i = p1 + t; i < hi; i += TPB)
                u_lds[i] = poll_u2(src + i, tgt);
        }
        __syncthreads();

        // ---- phase A (redundant halo, pure LDS): v = b/(K^T u + eps) ----
#pragma unroll
        for (int k = 0; k < 4; ++k) {
            int cn = ccnt[k];
            if (cn > 0) {
                float s = 0.f;
                int le = cofs[k];
                if (le + cn <= ENT_CAP) {
                    for (int e = 0; e < cn; ++e) {
                        unsigned E = ent_l[le + e];
                        s = fmaf(__uint_as_float(E & 0xFFFFFC00u), u_lds[E & 0x3FFu], s);
                    }
                } else {
                    for (int e = 0; e < cn; ++e) {   // overflow: L2 path
                        unsigned E = entC[e0 + le + e];
                        s = fmaf(__uint_as_float(E & 0xFFFFFC00u), u_lds[E & 0x3FFu], s);
                    }
                }
                v_loc[cvi[k]] = cb[k] / (s + EPSF);
            }
        }
        __syncthreads();

        // ---- phase B: u = A/(K v + eps); publish stamped u (contiguous) ----
        unsigned long long* dst = u2_g + (unsigned)(it & 1)*NPTS;
        const unsigned long long hi_stamp = ((unsigned long long)(unsigned)(it+1)) << 32;
        if (mypos >= 0) {
            float kv = 0.f, kd = 0.f;
#pragma unroll
            for (int k = 0; k < 13; ++k) {
                if (k < km) {
                    float vj = v_loc[cq[k]];
                    kv = fmaf(Kq[k],  vj, kv);
                    kd = fmaf(Kd2[k], vj, kd);
                }
            }
            kv += __shfl_xor(kv, 1); kv += __shfl_xor(kv, 2);
            float u_new = A / (kv + EPSF);
            if (sub == 0) {
                u_lds[mypos] = u_new;
                __hip_atomic_store(dst + mypos,
                                   hi_stamp | __float_as_uint(u_new),
                                   __ATOMIC_RELAXED, AGENT);
            }
            if (it == NITER-1) {
                kd += __shfl_xor(kd, 1); kd += __shfl_xor(kd, 2);
                if (sub == 0) li_acc += u_new * kd;
            }
        }
        // rare overflow (band with >128 points): compute K inline
        for (int base2 = 128; base2 < npts; base2 += 128) {
            int idx2 = base2 + idx;
            if (idx2 < npts) {
                int pos2 = p0 + idx2;
                int pid2 = (int)plist[pos2];
                float px = pts[(img*NPTS + pid2)*2 + 0];
                float py = pts[(img*NPTS + pid2)*2 + 1];
                int r_lo, c_lo; window_of(px, py, r_lo, c_lo);
                float kv = 0.f, kd = 0.f;
                for (int q = sub; q < 49; q += 4) {
                    int wy = q / 7, wx = q % 7;
                    float dx = px - (float)(8*(c_lo+wx) + 4);
                    float dy = py - (float)(8*(r_lo+wy) + 4);
                    float d2 = dx*dx + dy*dy;
                    float K = exp2f(C2 * d2);
                    float vj = v_loc[(r_lo + wy - rowbase)*GRID_N + c_lo + wx];
                    kv = fmaf(K, vj, kv); kd = fmaf(K*d2, vj, kd);
                }
                kv += __shfl_xor(kv, 1); kv += __shfl_xor(kv, 2);
                float u_new = A / (kv + EPSF);
                if (sub == 0) {
                    u_lds[pos2] = u_new;
                    __hip_atomic_store(dst + pos2,
                                       hi_stamp | __float_as_uint(u_new),
                                       __ATOMIC_RELAXED, AGENT);
                }
                if (it == NITER-1) {
                    kd += __shfl_xor(kd, 1); kd += __shfl_xor(kd, 2);
                    if (sub == 0) li_acc += u_new * kd;
                }
            }
        }
        __syncthreads();   // u_lds[own] final before next staging writes
    }

    // ---- loss reduction + last-WG finalize ----
#pragma unroll
    for (int o = 32; o > 0; o >>= 1) li_acc += __shfl_down(li_acc, o);
    if ((t & 63) == 0) red[t >> 6] = li_acc;
    __syncthreads();
    if (t == 0) {
        float s = 0.f;
#pragma unroll
        for (int w = 0; w < 8; ++w) s += red[w];
        atomicAdd(&loss[img], s);
        unsigned done = __hip_atomic_fetch_add(ws_u32 + 4, 1u,
                                               __ATOMIC_ACQ_REL, AGENT);
        if (done == (unsigned)(NIMG*NBAND - 1)) {
            float tot = 0.f;
#pragma unroll
            for (int i = 0; i < 4; ++i)
                tot += __hip_atomic_load(ws_f + i, __ATOMIC_RELAXED, AGENT);
            out[0] = tot;
            out[1] = tot;
            out[2] = 0.f;
        }
    }
}

// ---- fallback (ws too small): R1-verified single-kernel path ----
__global__ __launch_bounds__(1024) void ot_fallback_kernel(
    const float* __restrict__ dens, const float* __restrict__ pts,
    float* __restrict__ out)
{
    const int img = blockIdx.x, t = threadIdx.x;
    __shared__ float sv[NCELL];
    __shared__ float redf[16];

    const float px = pts[(size_t)img*NPTS*2 + t*2 + 0];
    const float py = pts[(size_t)img*NPTS*2 + t*2 + 1];
    int r_lo, c_lo; window_of(px, py, r_lo, c_lo);

    float dx2[WIN], dy2[WIN];
#pragma unroll
    for (int j = 0; j < WIN; ++j) {
        float dx = px - (float)(8*(c_lo+j) + 4);
        float dy = py - (float)(8*(r_lo+j) + 4);
        dx2[j] = dx*dx; dy2[j] = dy*dy;
    }
    float K[WIN*WIN];
#pragma unroll
    for (int wy = 0; wy < WIN; ++wy)
#pragma unroll
        for (int wx = 0; wx < WIN; ++wx)
            K[wy*WIN+wx] = exp2f(C2 * (dx2[wx] + dy2[wy]));

    const int lbase = r_lo*GRID_N + c_lo;
    float breg[16];
    const float4* d4 = (const float4*)(dens + (size_t)img*NCELL + t*16);
#pragma unroll
    for (int j = 0; j < 4; ++j) {
        float4 v = d4[j];
        breg[j*4+0]=v.x; breg[j*4+1]=v.y; breg[j*4+2]=v.z; breg[j*4+3]=v.w;
    }
    const float A = 1.0f/(float)NPTS;
    float u = A;
    float4* sv4 = (float4*)sv;
    for (int it = 0; it < NITER; ++it) {
        __syncthreads();
#pragma unroll
        for (int j = 0; j < 4; ++j) sv4[t*4+j] = make_float4(0.f,0.f,0.f,0.f);
        __syncthreads();
#pragma unroll
        for (int wy = 0; wy < WIN; ++wy)
#pragma unroll
            for (int wx = 0; wx < WIN; ++wx)
                atomicAdd(&sv[lbase + wy*GRID_N + wx], u * K[wy*WIN+wx]);
        __syncthreads();
#pragma unroll
        for (int j = 0; j < 16; ++j) { int c = t*16+j; sv[c] = breg[j] / (sv[c] + EPSF); }
        __syncthreads();
        float kv = 0.f;
#pragma unroll
        for (int wy = 0; wy < WIN; ++wy)
#pragma unroll
            for (int wx = 0; wx < WIN; ++wx)
                kv = fmaf(K[wy*WIN+wx], sv[lbase + wy*GRID_N + wx], kv);
        u = A / (kv + EPSF);
    }
    float li = 0.f;
#pragma unroll
    for (int wy = 0; wy < WIN; ++wy)
#pragma unroll
        for (int wx = 0; wx < WIN; ++wx)
            li = fmaf(K[wy*WIN+wx] * (dx2[wx]+dy2[wy]), sv[lbase + wy*GRID_N + wx], li);
    li *= u;
#pragma unroll
    for (int o = 32; o > 0; o >>= 1) li += __shfl_down(li, o);
    if ((t & 63) == 0) redf[t >> 6] = li;
    __syncthreads();
    if (t == 0) {
        float s = 0.f;
#pragma unroll
        for (int w = 0; w < 16; ++w) s += redf[w];
        atomicAdd(&out[0], s);
        atomicAdd(&out[1], s);
    }
}

extern "C" void kernel_launch(void* const* d_in, const int* in_sizes, int n_in,
                              void* d_out, int out_size, void* d_ws, size_t ws_size,
                              hipStream_t stream)
{
    const float* dens = (const float*)d_in[0];   // [4,1,128,128]
    const float* pts  = (const float*)d_in[2];   // [4,1024,2]
    float* out = (float*)d_out;
    unsigned* ws_u32 = (unsigned*)d_ws;

    if (ws_size < (size_t)WS_TOTAL) {   // insurance: slow-but-correct path
        hipMemsetAsync(d_out, 0, 3*sizeof(float), stream);
        ot_fallback_kernel<<<NIMG, 1024, 0, stream>>>(dens, pts, out);
        return;
    }

    hipMemsetAsync(d_ws, 0, ZERO_BYTES, stream);   // loss + done + stamps
    ot_setup_kernel<<<NIMG, 1024, 0, stream>>>(pts, ws_u32);
    ot_main_kernel <<<NIMG*NBAND, TPB, 0, stream>>>(dens, pts, ws_u32, out);
}

// Round 10
// 603.051 us; speedup vs baseline: 8082.3338x; 1.2614x over previous
//
#include <hip/hip_runtime.h>

// OT Sinkhorn loss. B=4 images, N=1024 pts, 128x128 grid, 100 iters.
// R10: CH=2 iteration chunking (sync every 2 iters; interaction radius is
// 3 rows per half-step) + FULL fusion (per-WG local CSR build + rank sort;
// no setup kernel, no global CSR). Sync = R8/R9 proven stamped monotone
// poll + chunk-parity double buffer. R9 was 509us main + 250us overhead:
// sync handshake ~4.5us/iter is mechanism-independent -> amortize it.

#define GRID_N 128
#define NCELL  16384
#define NPTS   1024
#define NIMG   4
#define NITER  100
#define NCHUNK 50
#define NBAND  16
#define TPB    512
#define V1ROWS 26
#define V1CELLS (V1ROWS*GRID_N)   // 3328
#define ENT_CAP 14336             // expected ~10.2K +- 0.8K
#define CPT 7                     // cells per thread in scan (7*512 >= 3328)

#define C2   (-0.14426950408889634f)   // -log2(e)/10
#define EPSF 1e-16f
#define AGENT __HIP_MEMORY_SCOPE_AGENT

// ws layout: [0..16) loss f32[4]; [16..20) done u32; [64..64+65536) u2
#define WS_U_B   64
#define WS_TOTAL (WS_U_B + NIMG*2*NPTS*8)
#define ZERO_BYTES WS_TOTAL

__device__ __forceinline__ void window_of(float px, float py, int& r_lo, int& c_lo)
{
    int kc = (int)(px * 0.125f); kc = kc < 0 ? 0 : (kc > GRID_N-1 ? GRID_N-1 : kc);
    int kr = (int)(py * 0.125f); kr = kr < 0 ? 0 : (kr > GRID_N-1 ? GRID_N-1 : kr);
    c_lo = kc - 3; c_lo = c_lo < 0 ? 0 : (c_lo > GRID_N-7 ? GRID_N-7 : c_lo);
    r_lo = kr - 3; r_lo = r_lo < 0 ? 0 : (r_lo > GRID_N-7 ? GRID_N-7 : r_lo);
}

__device__ __forceinline__ float poll_u2(const unsigned long long* addr, unsigned target)
{
    unsigned long long w = __hip_atomic_load(addr, __ATOMIC_RELAXED, AGENT);
    int spins = 0;
    while ((unsigned)(w >> 32) < target) {
        __builtin_amdgcn_s_sleep(1);
        w = __hip_atomic_load(addr, __ATOMIC_RELAXED, AGENT);
        if (++spins > (1<<22)) break;   // monotone stamp => unreachable
    }
    return __uint_as_float((unsigned)w);
}

__global__ __launch_bounds__(TPB) void ot_main_kernel(
    const float* __restrict__ dens, const float* __restrict__ pts,
    unsigned* __restrict__ ws_u32, float* __restrict__ out)
{
    const int img = (int)blockIdx.x >> 4, bnd = (int)blockIdx.x & 15;
    const int t = threadIdx.x;
    float* ws_f = (float*)ws_u32;
    unsigned long long* u2_g =
        (unsigned long long*)((char*)ws_u32 + WS_U_B) + img*2*NPTS;

    __shared__ float    vbuf[V1CELLS];     // v over V1 rows (aliased cnt in build)
    __shared__ float    densV1[V1CELLS];
    __shared__ unsigned offs[V1CELLS + 1];
    __shared__ unsigned ent[ENT_CAP];      // {K22 | slot10}
    __shared__ float    u_lds[NPTS];       // u^{2c}, slot-indexed
    __shared__ float    u_mid[NPTS];       // u^{2c+1} (aliased keys in init)
    __shared__ float    px_l[NPTS], py_l[NPTS];
    __shared__ unsigned bofs[17];
    __shared__ unsigned cnt16[16];
    __shared__ unsigned swsum[9];
    __shared__ float    red[8];

    const int v1lo = (bnd*8-9) < 0 ? 0 : (bnd*8-9);
    const int v1hi = (bnd*8+16) > 127 ? 127 : (bnd*8+16);
    const int cells = (v1hi - v1lo + 1) * GRID_N;
    const int v2lo = (bnd*8-3) < 0 ? 0 : (bnd*8-3);
    const int v2hi = (bnd*8+10) > 127 ? 127 : (bnd*8+10);
    const int a2c0 = (v2lo - v1lo)*GRID_N, a2c1 = (v2hi - v1lo + 1)*GRID_N;
    const int p1lo = (bnd*8-6) < 0 ? 0 : (bnd*8-6);
    const int p1hi = (bnd*8+13) > 127 ? 127 : (bnd*8+13);
    const float A = 1.0f / (float)NPTS;

    unsigned* keys = (unsigned*)u_mid;     // alias during init only
    unsigned* cnt  = (unsigned*)vbuf;      // alias during build only

    // ---- init 1: load pts, keys, histogram ----
    float mpx[2], mpy[2]; int mband[2]; unsigned mkey[2];
#pragma unroll
    for (int j = 0; j < 2; ++j) {
        int p = t + j*TPB;
        mpx[j] = pts[(img*NPTS + p)*2 + 0];
        mpy[j] = pts[(img*NPTS + p)*2 + 1];
        int kr = (int)(mpy[j] * 0.125f); kr = kr < 0 ? 0 : (kr > 127 ? 127 : kr);
        mband[j] = kr >> 3;
        mkey[j] = ((unsigned)mband[j] << 10) | (unsigned)p;
        keys[p] = mkey[j];
    }
    if (t < 16) cnt16[t] = 0;
    __syncthreads();
#pragma unroll
    for (int j = 0; j < 2; ++j) atomicAdd(&cnt16[mband[j]], 1u);
    __syncthreads();
    if (t == 0) {
        unsigned run = 0;
        for (int i = 0; i < 16; ++i) { bofs[i] = run; run += cnt16[i]; }
        bofs[16] = run;
    }
    __syncthreads();

    // ---- init 2: deterministic rank sort (key = band<<10 | pid) ----
    {
        int r0 = 0, r1 = 0;
        for (int q = 0; q < NPTS; ++q) {
            unsigned kq = keys[q];
            r0 += (kq < mkey[0]); r1 += (kq < mkey[1]);
        }
        px_l[r0] = mpx[0]; py_l[r0] = mpy[0]; u_lds[r0] = A;
        px_l[r1] = mpx[1]; py_l[r1] = mpy[1]; u_lds[r1] = A;
    }
    __syncthreads();   // keys dead from here; u_mid usable

    // ---- init 3: densV1 + zero cnt ----
    for (int i = t; i < cells; i += TPB) {
        densV1[i] = dens[img*NCELL + v1lo*GRID_N + i];
        cnt[i] = 0u;
    }
    const int s0 = (int)bofs[bnd > 1 ? bnd-2 : 0];
    const int s1 = (int)bofs[(bnd < 14 ? bnd+2 : 15) + 1];
    __syncthreads();

    // ---- init 4: local CSR count ----
    for (int i = s0 + t; i < s1; i += TPB) {
        int r_lo, c_lo; window_of(px_l[i], py_l[i], r_lo, c_lo);
#pragma unroll
        for (int wy = 0; wy < 7; ++wy) {
            int row = r_lo + wy;
            if (row >= v1lo && row <= v1hi) {
                int base = (row - v1lo)*GRID_N + c_lo;
#pragma unroll
                for (int wx = 0; wx < 7; ++wx) atomicAdd(&cnt[base + wx], 1u);
            }
        }
    }
    __syncthreads();

    // ---- init 5: exclusive scan cnt -> offs ----
    {
        const int c0 = t*CPT;
        unsigned lc[CPT]; unsigned csum = 0;
#pragma unroll
        for (int k = 0; k < CPT; ++k) {
            int ci = c0 + k;
            lc[k] = (ci < cells) ? cnt[ci] : 0u;
            csum += lc[k];
        }
        unsigned inc = csum;
        const int lane = t & 63;
#pragma unroll
        for (int d = 1; d < 64; d <<= 1) {
            unsigned x = __shfl_up(inc, d, 64);
            if (lane >= d) inc += x;
        }
        if (lane == 63) swsum[t >> 6] = inc;
        __syncthreads();
        if (t < 8) {
            unsigned wv = swsum[t], winc = wv;
#pragma unroll
            for (int d = 1; d < 8; d <<= 1) {
                unsigned x = __shfl_up(winc, d, 8);
                if (t >= d) winc += x;
            }
            swsum[t] = winc - wv;
            if (t == 7) swsum[8] = winc;   // grand total
        }
        __syncthreads();
        unsigned run = swsum[t >> 6] + (inc - csum);
#pragma unroll
        for (int k = 0; k < CPT; ++k) {
            int ci = c0 + k;
            if (ci < cells) { offs[ci] = run; run += lc[k]; }
        }
        if (t == 0) offs[cells] = swsum[8];
    }
    __syncthreads();

    // ---- init 6: CSR fill {K22|slot10} (drains cnt) ----
    for (int i = s0 + t; i < s1; i += TPB) {
        float px = px_l[i], py = py_l[i];
        int r_lo, c_lo; window_of(px, py, r_lo, c_lo);
#pragma unroll
        for (int wy = 0; wy < 7; ++wy) {
            int row = r_lo + wy;
            if (row >= v1lo && row <= v1hi) {
                float dy = py - (float)(8*row + 4);
                int base = (row - v1lo)*GRID_N + c_lo;
#pragma unroll
                for (int wx = 0; wx < 7; ++wx) {
                    float dx = px - (float)(8*(c_lo+wx) + 4);
                    float K = exp2f(C2 * (dx*dx + dy*dy));
                    unsigned e = ((__float_as_uint(K) + 0x200u) & 0xFFFFFC00u)
                               | (unsigned)i;
                    unsigned old = atomicSub(&cnt[base + wx], 1u);
                    unsigned idx = offs[base + wx] + old - 1u;
                    if (idx < ENT_CAP) ent[idx] = e;
                }
            }
        }
    }

    // ---- init 7: B2 prestored K (4 threads/point) ----
    const int p0 = (int)bofs[bnd];
    const int pn = (int)bofs[bnd+1] - p0;
    const int sub = t & 3, idx4 = t >> 2;
    int km = 0;
    float Kq[13], Kd2[13]; int cq[13];
    if (idx4 < pn && idx4 < 128) {
        float px = px_l[p0 + idx4], py = py_l[p0 + idx4];
        int r_lo, c_lo; window_of(px, py, r_lo, c_lo);
        int k = 0;
#pragma unroll
        for (int q = 0; q < 49; ++q) {
            if ((q & 3) == sub) {
                int wy = q / 7, wx = q % 7;
                float dx = px - (float)(8*(c_lo+wx) + 4);
                float dy = py - (float)(8*(r_lo+wy) + 4);
                float d2 = dx*dx + dy*dy;
                float K = exp2f(C2 * d2);
                Kq[k] = K; Kd2[k] = K * d2;
                cq[k] = (r_lo + wy - v1lo)*GRID_N + (c_lo + wx);
                ++k;
            }
        }
        km = k;
    }
    const int b1s = (int)bofs[bnd > 0 ? bnd-1 : 0];
    const int b1e = (int)bofs[(bnd < 15 ? bnd+1 : 15) + 1];
    __syncthreads();

    float li_acc = 0.f;

    // ================= chunk loop: 2 Sinkhorn iters per sync =================
    for (int c = 0; c < NCHUNK; ++c) {
        if (c > 0) {
            const unsigned long long* src = u2_g + (unsigned)((c-1) & 1)*NPTS;
            const unsigned tgt = (unsigned)c;
            for (int i = s0 + t; i < p0; i += TPB)
                u_lds[i] = poll_u2(src + i, tgt);
            for (int i = p0 + pn + t; i < s1; i += TPB)
                u_lds[i] = poll_u2(src + i, tgt);
        }
        __syncthreads();

        // A1: v^{2c+1} over V1 rows (gather, u_lds)
        for (int ci = t; ci < cells; ci += TPB) {
            float s = 0.f;
            unsigned e1 = offs[ci+1]; if (e1 > ENT_CAP) e1 = ENT_CAP;
            for (unsigned e = offs[ci]; e < e1; ++e) {
                unsigned E = ent[e];
                s = fmaf(__uint_as_float(E & 0xFFFFFC00u), u_lds[E & 0x3FFu], s);
            }
            vbuf[ci] = densV1[ci] / (s + EPSF);
        }
        __syncthreads();

        // B1: u^{2c+1} for points kr in [p1lo, p1hi] (K inline)
        for (int i = b1s + t; i < b1e; i += TPB) {
            float py = py_l[i];
            int kr = (int)(py * 0.125f); kr = kr < 0 ? 0 : (kr > 127 ? 127 : kr);
            if (kr < p1lo || kr > p1hi) continue;
            float px = px_l[i];
            int r_lo, c_lo; window_of(px, py, r_lo, c_lo);
            float kv = 0.f;
#pragma unroll
            for (int wy = 0; wy < 7; ++wy) {
                float dy = py - (float)(8*(r_lo+wy) + 4);
                float dy2 = dy*dy;
                int rb = (r_lo + wy - v1lo)*GRID_N + c_lo;
#pragma unroll
                for (int wx = 0; wx < 7; ++wx) {
                    float dx = px - (float)(8*(c_lo+wx) + 4);
                    float K = exp2f(C2 * (dx*dx + dy2));
                    kv = fmaf(K, vbuf[rb + wx], kv);
                }
            }
            u_mid[i] = A / (kv + EPSF);
        }
        __syncthreads();

        // A2: v^{2c+2} over V2 rows (gather, u_mid)
        for (int ci = a2c0 + t; ci < a2c1; ci += TPB) {
            float s = 0.f;
            unsigned e1 = offs[ci+1]; if (e1 > ENT_CAP) e1 = ENT_CAP;
            for (unsigned e = offs[ci]; e < e1; ++e) {
                unsigned E = ent[e];
                s = fmaf(__uint_as_float(E & 0xFFFFFC00u), u_mid[E & 0x3FFu], s);
            }
            vbuf[ci] = densV1[ci] / (s + EPSF);
        }
        __syncthreads();

        // B2: u^{2c+2} for own points; publish stamped
        unsigned long long* dst = u2_g + (unsigned)(c & 1)*NPTS;
        const unsigned long long hs = ((unsigned long long)(unsigned)(c+1)) << 32;
        const bool last = (c == NCHUNK-1);
        if (idx4 < pn && idx4 < 128) {
            float kv = 0.f, kd = 0.f;
#pragma unroll
            for (int k = 0; k < 13; ++k) {
                if (k < km) {
                    float vj = vbuf[cq[k]];
                    kv = fmaf(Kq[k],  vj, kv);
                    kd = fmaf(Kd2[k], vj, kd);
                }
            }
            kv += __shfl_xor(kv, 1); kv += __shfl_xor(kv, 2);
            float u_new = A / (kv + EPSF);
            if (sub == 0) {
                u_lds[p0 + idx4] = u_new;
                __hip_atomic_store(dst + p0 + idx4,
                                   hs | __float_as_uint(u_new),
                                   __ATOMIC_RELAXED, AGENT);
            }
            if (last) {
                kd += __shfl_xor(kd, 1); kd += __shfl_xor(kd, 2);
                if (sub == 0) li_acc += u_new * kd;
            }
        }
        for (int b2 = 128; b2 < pn; b2 += 128) {   // rare overflow
            int i2 = b2 + idx4;
            if (i2 < pn) {
                int sl = p0 + i2;
                float px = px_l[sl], py = py_l[sl];
                int r_lo, c_lo; window_of(px, py, r_lo, c_lo);
                float kv = 0.f, kd = 0.f;
                for (int q = sub; q < 49; q += 4) {
                    int wy = q / 7, wx = q % 7;
                    float dx = px - (float)(8*(c_lo+wx) + 4);
                    float dy = py - (float)(8*(r_lo+wy) + 4);
                    float d2 = dx*dx + dy*dy;
                    float K = exp2f(C2 * d2);
                    float vj = vbuf[(r_lo + wy - v1lo)*GRID_N + c_lo + wx];
                    kv = fmaf(K, vj, kv); kd = fmaf(K*d2, vj, kd);
                }
                kv += __shfl_xor(kv, 1); kv += __shfl_xor(kv, 2);
                float u_new = A / (kv + EPSF);
                if (sub == 0) {
                    u_lds[sl] = u_new;
                    __hip_atomic_store(dst + sl, hs | __float_as_uint(u_new),
                                       __ATOMIC_RELAXED, AGENT);
                }
                if (last) {
                    kd += __shfl_xor(kd, 1); kd += __shfl_xor(kd, 2);
                    if (sub == 0) li_acc += u_new * kd;
                }
            }
        }
        __syncthreads();
    }

    // ---- loss reduction + last-WG finalize ----
#pragma unroll
    for (int o = 32; o > 0; o >>= 1) li_acc += __shfl_down(li_acc, o);
    if ((t & 63) == 0) red[t >> 6] = li_acc;
    __syncthreads();
    if (t == 0) {
        float s = 0.f;
#pragma unroll
        for (int w = 0; w < 8; ++w) s += red[w];
        atomicAdd(&ws_f[img], s);
        unsigned done = __hip_atomic_fetch_add(ws_u32 + 4, 1u,
                                               __ATOMIC_ACQ_REL, AGENT);
        if (done == (unsigned)(NIMG*NBAND - 1)) {
            float tot = 0.f;
#pragma unroll
            for (int i = 0; i < 4; ++i)
                tot += __hip_atomic_load(ws_f + i, __ATOMIC_RELAXED, AGENT);
            out[0] = tot;
            out[1] = tot;
            out[2] = 0.f;
        }
    }
}

// ---- fallback (ws too small): R1-verified single-kernel path ----
__global__ __launch_bounds__(1024) void ot_fallback_kernel(
    const float* __restrict__ dens, const float* __restrict__ pts,
    float* __restrict__ out)
{
    const int img = blockIdx.x, t = threadIdx.x;
    __shared__ float sv[NCELL];
    __shared__ float redf[16];

    const float px = pts[(size_t)img*NPTS*2 + t*2 + 0];
    const float py = pts[(size_t)img*NPTS*2 + t*2 + 1];
    int r_lo, c_lo; window_of(px, py, r_lo, c_lo);

    float dx2[7], dy2[7];
#pragma unroll
    for (int j = 0; j < 7; ++j) {
        float dx = px - (float)(8*(c_lo+j) + 4);
        float dy = py - (float)(8*(r_lo+j) + 4);
        dx2[j] = dx*dx; dy2[j] = dy*dy;
    }
    float K[49];
#pragma unroll
    for (int wy = 0; wy < 7; ++wy)
#pragma unroll
        for (int wx = 0; wx < 7; ++wx)
            K[wy*7+wx] = exp2f(C2 * (dx2[wx] + dy2[wy]));

    const int lbase = r_lo*GRID_N + c_lo;
    float breg[16];
    const float4* d4 = (const float4*)(dens + (size_t)img*NCELL + t*16);
#pragma unroll
    for (int j = 0; j < 4; ++j) {
        float4 v = d4[j];
        breg[j*4+0]=v.x; breg[j*4+1]=v.y; breg[j*4+2]=v.z; breg[j*4+3]=v.w;
    }
    const float A = 1.0f/(float)NPTS;
    float u = A;
    float4* sv4 = (float4*)sv;
    for (int it = 0; it < NITER; ++it) {
        __syncthreads();
#pragma unroll
        for (int j = 0; j < 4; ++j) sv4[t*4+j] = make_float4(0.f,0.f,0.f,0.f);
        __syncthreads();
#pragma unroll
        for (int wy = 0; wy < 7; ++wy)
#pragma unroll
            for (int wx = 0; wx < 7; ++wx)
                atomicAdd(&sv[lbase + wy*GRID_N + wx], u * K[wy*7+wx]);
        __syncthreads();
#pragma unroll
        for (int j = 0; j < 16; ++j) { int c = t*16+j; sv[c] = breg[j] / (sv[c] + EPSF); }
        __syncthreads();
        float kv = 0.f;
#pragma unroll
        for (int wy = 0; wy < 7; ++wy)
#pragma unroll
            for (int wx = 0; wx < 7; ++wx)
                kv = fmaf(K[wy*7+wx], sv[lbase + wy*GRID_N + wx], kv);
        u = A / (kv + EPSF);
    }
    float li = 0.f;
#pragma unroll
    for (int wy = 0; wy < 7; ++wy)
#pragma unroll
        for (int wx = 0; wx < 7; ++wx)
            li = fmaf(K[wy*7+wx] * (dx2[wx]+dy2[wy]), sv[lbase + wy*GRID_N + wx], li);
    li *= u;
#pragma unroll
    for (int o = 32; o > 0; o >>= 1) li += __shfl_down(li, o);
    if ((t & 63) == 0) redf[t >> 6] = li;
    __syncthreads();
    if (t == 0) {
        float s = 0.f;
#pragma unroll
        for (int w = 0; w < 16; ++w) s += redf[w];
        atomicAdd(&out[0], s);
        atomicAdd(&out[1], s);
    }
}

extern "C" void kernel_launch(void* const* d_in, const int* in_sizes, int n_in,
                              void* d_out, int out_size, void* d_ws, size_t ws_size,
                              hipStream_t stream)
{
    const float* dens = (const float*)d_in[0];   // [4,1,128,128]
    const float* pts  = (const float*)d_in[2];   // [4,1024,2]
    float* out = (float*)d_out;
    unsigned* ws_u32 = (unsigned*)d_ws;

    if (ws_size < (size_t)WS_TOTAL) {   // insurance: slow-but-correct path
        hipMemsetAsync(d_out, 0, 3*sizeof(float), stream);
        ot_fallback_kernel<<<NIMG, 1024, 0, stream>>>(dens, pts, out);
        return;
    }

    hipMemsetAsync(d_ws, 0, ZERO_BYTES, stream);   // loss + done + u2 stamps
    ot_main_kernel<<<NIMG*NBAND, TPB, 0, stream>>>(dens, pts, ws_u32, out);
}

// Round 11
// 509.023 us; speedup vs baseline: 9575.3230x; 1.1847x over previous
//
#include <hip/hip_runtime.h>

// OT Sinkhorn loss. B=4 images, N=1024 pts, 128x128 grid, 100 iters.
// R11: bounded-staleness sync. R9's per-iter structure (CH=1, 14-row halo,
// narrowest +-1 band deps) but poll target = it-4 (slack) for iters 0..93:
// steady-state staging = 1 load, NO handshake. Strict (R9 proto) last 6
// iters. Basis: R6's accidental chaos run -> absmax 0.0 (fixpoint unique
// up to scaling the loss is invariant to; contraction => async converges;
// Bertsekas async iteration theory). R10 proved fused init; chunking
// REGRESSED main (sync cost scales with dep width, not event count).

#define GRID_N 128
#define NCELL  16384
#define NPTS   1024
#define NIMG   4
#define NITER  100
#define STRICT_AT 94
#define SLACK  4
#define NBAND  16
#define TPB    512
#define VROWS  14
#define VCELLS (VROWS*GRID_N)   // 1792
#define ENT_CAP 12288           // expected ~5.5K entries/band (14 rows)
#define CPT 4                   // cells/thread in scan (4*512 >= 1792)

#define C2   (-0.14426950408889634f)   // -log2(e)/10
#define EPSF 1e-16f
#define AGENT __HIP_MEMORY_SCOPE_AGENT

// ws: [0..16) loss f32[4]; [16..20) done; [20..24) gate; [64..) u2 stamps
#define WS_U_B   64
#define WS_TOTAL (WS_U_B + NIMG*2*NPTS*8)
#define ZERO_BYTES WS_TOTAL

__device__ __forceinline__ void window_of(float px, float py, int& r_lo, int& c_lo)
{
    int kc = (int)(px * 0.125f); kc = kc < 0 ? 0 : (kc > GRID_N-1 ? GRID_N-1 : kc);
    int kr = (int)(py * 0.125f); kr = kr < 0 ? 0 : (kr > GRID_N-1 ? GRID_N-1 : kr);
    c_lo = kc - 3; c_lo = c_lo < 0 ? 0 : (c_lo > GRID_N-7 ? GRID_N-7 : c_lo);
    r_lo = kr - 3; r_lo = r_lo < 0 ? 0 : (r_lo > GRID_N-7 ? GRID_N-7 : r_lo);
}

__device__ __forceinline__ float poll_u2(const unsigned long long* addr, int target)
{
    unsigned long long w = __hip_atomic_load(addr, __ATOMIC_RELAXED, AGENT);
    int spins = 0;
    while ((int)(unsigned)(w >> 32) < target) {
        __builtin_amdgcn_s_sleep(1);
        w = __hip_atomic_load(addr, __ATOMIC_RELAXED, AGENT);
        if (++spins > (1<<22)) break;   // monotone stamp => unreachable
    }
    return __uint_as_float((unsigned)w);
}

__global__ __launch_bounds__(TPB) void ot_main_kernel(
    const float* __restrict__ dens, const float* __restrict__ pts,
    unsigned* __restrict__ ws_u32, float* __restrict__ out)
{
    const int img = (int)blockIdx.x >> 4, bnd = (int)blockIdx.x & 15;
    const int t = threadIdx.x;
    float* ws_f = (float*)ws_u32;
    unsigned long long* u2_g =
        (unsigned long long*)((char*)ws_u32 + WS_U_B) + img*2*NPTS;

    __shared__ float    vbuf[VCELLS];      // v (aliased cnt during build)
    __shared__ float    densV[VCELLS];
    __shared__ unsigned offs[VCELLS + 1];
    __shared__ unsigned ent[ENT_CAP];      // {K22 | slot10}
    __shared__ float    u_lds[NPTS];       // slot-indexed
    __shared__ float    px_l[NPTS], py_l[NPTS];
    __shared__ unsigned keys_s[NPTS];
    __shared__ unsigned bofs[17];
    __shared__ unsigned cnt16[16];
    __shared__ unsigned swsum[9];
    __shared__ float    red[8];

    const int v1lo = (bnd*8-3) < 0 ? 0 : (bnd*8-3);
    const int v1hi = (bnd*8+10) > 127 ? 127 : (bnd*8+10);
    const int cells = (v1hi - v1lo + 1) * GRID_N;
    const float A = 1.0f / (float)NPTS;

    unsigned* cnt = (unsigned*)vbuf;       // alias during build only

    // ---- init 1: load pts, keys, band histogram ----
    float mpx[2], mpy[2]; int mband[2]; unsigned mkey[2];
#pragma unroll
    for (int j = 0; j < 2; ++j) {
        int p = t + j*TPB;
        mpx[j] = pts[(img*NPTS + p)*2 + 0];
        mpy[j] = pts[(img*NPTS + p)*2 + 1];
        int kr = (int)(mpy[j] * 0.125f); kr = kr < 0 ? 0 : (kr > 127 ? 127 : kr);
        mband[j] = kr >> 3;
        mkey[j] = ((unsigned)mband[j] << 10) | (unsigned)p;
        keys_s[p] = mkey[j];
    }
    if (t < 16) cnt16[t] = 0;
    __syncthreads();
#pragma unroll
    for (int j = 0; j < 2; ++j) atomicAdd(&cnt16[mband[j]], 1u);
    __syncthreads();
    if (t == 0) {
        unsigned run = 0;
        for (int i = 0; i < 16; ++i) { bofs[i] = run; run += cnt16[i]; }
        bofs[16] = run;
    }
    __syncthreads();

    // ---- init 2: deterministic rank sort (key = band<<10 | pid) ----
    {
        int r0 = 0, r1 = 0;
        for (int q = 0; q < NPTS; ++q) {
            unsigned kq = keys_s[q];
            r0 += (kq < mkey[0]); r1 += (kq < mkey[1]);
        }
        px_l[r0] = mpx[0]; py_l[r0] = mpy[0]; u_lds[r0] = A;
        px_l[r1] = mpx[1]; py_l[r1] = mpy[1]; u_lds[r1] = A;
    }
    __syncthreads();

    // ---- init 3: densV + zero cnt ----
    for (int i = t; i < cells; i += TPB) {
        densV[i] = dens[img*NCELL + v1lo*GRID_N + i];
        cnt[i] = 0u;
    }
    const int s0 = (int)bofs[bnd > 0 ? bnd-1 : 0];
    const int s1 = (int)bofs[(bnd < 15 ? bnd+1 : 15) + 1];
    const int p0 = (int)bofs[bnd];
    const int pn = (int)bofs[bnd+1] - p0;
    __syncthreads();

    // ---- init 4: local CSR count (points of bands b-1..b+1) ----
    for (int i = s0 + t; i < s1; i += TPB) {
        int r_lo, c_lo; window_of(px_l[i], py_l[i], r_lo, c_lo);
#pragma unroll
        for (int wy = 0; wy < 7; ++wy) {
            int row = r_lo + wy;
            if (row >= v1lo && row <= v1hi) {
                int base = (row - v1lo)*GRID_N + c_lo;
#pragma unroll
                for (int wx = 0; wx < 7; ++wx) atomicAdd(&cnt[base + wx], 1u);
            }
        }
    }
    __syncthreads();

    // ---- init 5: exclusive scan cnt -> offs ----
    {
        const int c0 = t*CPT;
        unsigned lc[CPT]; unsigned csum = 0;
#pragma unroll
        for (int k = 0; k < CPT; ++k) {
            int ci = c0 + k;
            lc[k] = (ci < cells) ? cnt[ci] : 0u;
            csum += lc[k];
        }
        unsigned inc = csum;
        const int lane = t & 63;
#pragma unroll
        for (int d = 1; d < 64; d <<= 1) {
            unsigned x = __shfl_up(inc, d, 64);
            if (lane >= d) inc += x;
        }
        if (lane == 63) swsum[t >> 6] = inc;
        __syncthreads();
        if (t < 8) {
            unsigned wv = swsum[t], winc = wv;
#pragma unroll
            for (int d = 1; d < 8; d <<= 1) {
                unsigned x = __shfl_up(winc, d, 8);
                if (t >= d) winc += x;
            }
            swsum[t] = winc - wv;
            if (t == 7) swsum[8] = winc;
        }
        __syncthreads();
        unsigned run = swsum[t >> 6] + (inc - csum);
#pragma unroll
        for (int k = 0; k < CPT; ++k) {
            int ci = c0 + k;
            if (ci < cells) { offs[ci] = run; run += lc[k]; }
        }
        if (t == 0) offs[cells] = swsum[8];
    }
    __syncthreads();

    // ---- init 6: CSR fill {K22|slot10} (drains cnt) ----
    for (int i = s0 + t; i < s1; i += TPB) {
        float px = px_l[i], py = py_l[i];
        int r_lo, c_lo; window_of(px, py, r_lo, c_lo);
#pragma unroll
        for (int wy = 0; wy < 7; ++wy) {
            int row = r_lo + wy;
            if (row >= v1lo && row <= v1hi) {
                float dy = py - (float)(8*row + 4);
                int base = (row - v1lo)*GRID_N + c_lo;
#pragma unroll
                for (int wx = 0; wx < 7; ++wx) {
                    float dx = px - (float)(8*(c_lo+wx) + 4);
                    float K = exp2f(C2 * (dx*dx + dy*dy));
                    unsigned e = ((__float_as_uint(K) + 0x200u) & 0xFFFFFC00u)
                               | (unsigned)i;
                    unsigned old = atomicSub(&cnt[base + wx], 1u);
                    unsigned idx = offs[base + wx] + old - 1u;
                    if (idx < ENT_CAP) ent[idx] = e;
                }
            }
        }
    }

    // ---- init 7: prestored K for own points (4 threads/point) ----
    const int sub = t & 3, idx4 = t >> 2;
    int km = 0;
    float Kq[13], Kd2[13]; int cq[13];
    if (idx4 < pn && idx4 < 128) {
        float px = px_l[p0 + idx4], py = py_l[p0 + idx4];
        int r_lo, c_lo; window_of(px, py, r_lo, c_lo);
        int k = 0;
#pragma unroll
        for (int q = 0; q < 49; ++q) {
            if ((q & 3) == sub) {
                int wy = q / 7, wx = q % 7;
                float dx = px - (float)(8*(c_lo+wx) + 4);
                float dy = py - (float)(8*(r_lo+wy) + 4);
                float d2 = dx*dx + dy*dy;
                float K = exp2f(C2 * d2);
                Kq[k] = K; Kd2[k] = K * d2;
                cq[k] = (r_lo + wy - v1lo)*GRID_N + (c_lo + wx);
                ++k;
            }
        }
        km = k;
    }

    // ---- init 8: seed both parity buffers with {stamp0, A}; global gate ----
    for (int i = p0 + t; i < p0 + pn; i += TPB) {
        unsigned long long seed = (unsigned long long)__float_as_uint(A);
        __hip_atomic_store(u2_g + i,        seed, __ATOMIC_RELAXED, AGENT);
        __hip_atomic_store(u2_g + NPTS + i, seed, __ATOMIC_RELAXED, AGENT);
    }
    __syncthreads();
    if (t == 0) {
        __hip_atomic_fetch_add(ws_u32 + 5, 1u, __ATOMIC_ACQ_REL, AGENT);
        int spins = 0;
        while (__hip_atomic_load(ws_u32 + 5, __ATOMIC_ACQUIRE, AGENT)
               < (unsigned)(NIMG*NBAND)) {
            __builtin_amdgcn_s_sleep(2);
            if (++spins > (1<<22)) break;
        }
    }
    __syncthreads();

    float li_acc = 0.f;

    // ============ iteration loop: slack poll 0..93, strict 94..99 ============
    for (int it = 0; it < NITER; ++it) {
        if (it > 0) {
            const unsigned long long* src = u2_g + (unsigned)((it-1) & 1)*NPTS;
            const int tgt = (it >= STRICT_AT) ? it
                          : (it > SLACK ? it - SLACK : 0);
            for (int i = s0 + t; i < p0; i += TPB)
                u_lds[i] = poll_u2(src + i, tgt);
            for (int i = p0 + pn + t; i < s1; i += TPB)
                u_lds[i] = poll_u2(src + i, tgt);
        }
        __syncthreads();

        // ---- phase A: v = b / (K^T u + eps), 14-row halo, pure LDS ----
        for (int ci = t; ci < cells; ci += TPB) {
            float s = 0.f;
            unsigned e1 = offs[ci+1]; if (e1 > ENT_CAP) e1 = ENT_CAP;
            for (unsigned e = offs[ci]; e < e1; ++e) {
                unsigned E = ent[e];
                s = fmaf(__uint_as_float(E & 0xFFFFFC00u), u_lds[E & 0x3FFu], s);
            }
            vbuf[ci] = densV[ci] / (s + EPSF);
        }
        __syncthreads();

        // ---- phase B: u = A / (K v + eps); publish stamped ----
        unsigned long long* dst = u2_g + (unsigned)(it & 1)*NPTS;
        const unsigned long long hs = ((unsigned long long)(unsigned)(it+1)) << 32;
        const bool last = (it == NITER-1);
        if (idx4 < pn && idx4 < 128) {
            float kv = 0.f, kd = 0.f;
#pragma unroll
            for (int k = 0; k < 13; ++k) {
                if (k < km) {
                    float vj = vbuf[cq[k]];
                    kv = fmaf(Kq[k],  vj, kv);
                    kd = fmaf(Kd2[k], vj, kd);
                }
            }
            kv += __shfl_xor(kv, 1); kv += __shfl_xor(kv, 2);
            float u_new = A / (kv + EPSF);
            if (sub == 0) {
                u_lds[p0 + idx4] = u_new;
                __hip_atomic_store(dst + p0 + idx4,
                                   hs | __float_as_uint(u_new),
                                   __ATOMIC_RELAXED, AGENT);
            }
            if (last) {
                kd += __shfl_xor(kd, 1); kd += __shfl_xor(kd, 2);
                if (sub == 0) li_acc += u_new * kd;
            }
        }
        for (int b2 = 128; b2 < pn; b2 += 128) {   // rare overflow
            int i2 = b2 + idx4;
            if (i2 < pn) {
                int sl = p0 + i2;
                float px = px_l[sl], py = py_l[sl];
                int r_lo, c_lo; window_of(px, py, r_lo, c_lo);
                float kv = 0.f, kd = 0.f;
                for (int q = sub; q < 49; q += 4) {
                    int wy = q / 7, wx = q % 7;
                    float dx = px - (float)(8*(c_lo+wx) + 4);
                    float dy = py - (float)(8*(r_lo+wy) + 4);
                    float d2 = dx*dx + dy*dy;
                    float K = exp2f(C2 * d2);
                    float vj = vbuf[(r_lo + wy - v1lo)*GRID_N + c_lo + wx];
                    kv = fmaf(K, vj, kv); kd = fmaf(K*d2, vj, kd);
                }
                kv += __shfl_xor(kv, 1); kv += __shfl_xor(kv, 2);
                float u_new = A / (kv + EPSF);
                if (sub == 0) {
                    u_lds[sl] = u_new;
                    __hip_atomic_store(dst + sl, hs | __float_as_uint(u_new),
                                       __ATOMIC_RELAXED, AGENT);
                }
                if (last) {
                    kd += __shfl_xor(kd, 1); kd += __shfl_xor(kd, 2);
                    if (sub == 0) li_acc += u_new * kd;
                }
            }
        }
        __syncthreads();
    }

    // ---- loss reduction + last-WG finalize ----
#pragma unroll
    for (int o = 32; o > 0; o >>= 1) li_acc += __shfl_down(li_acc, o);
    if ((t & 63) == 0) red[t >> 6] = li_acc;
    __syncthreads();
    if (t == 0) {
        float s = 0.f;
#pragma unroll
        for (int w = 0; w < 8; ++w) s += red[w];
        atomicAdd(&ws_f[img], s);
        unsigned done = __hip_atomic_fetch_add(ws_u32 + 4, 1u,
                                               __ATOMIC_ACQ_REL, AGENT);
        if (done == (unsigned)(NIMG*NBAND - 1)) {
            float tot = 0.f;
#pragma unroll
            for (int i = 0; i < 4; ++i)
                tot += __hip_atomic_load(ws_f + i, __ATOMIC_RELAXED, AGENT);
            out[0] = tot;
            out[1] = tot;
            out[2] = 0.f;
        }
    }
}

// ---- fallback (ws too small): R1-verified single-kernel path ----
__global__ __launch_bounds__(1024) void ot_fallback_kernel(
    const float* __restrict__ dens, const float* __restrict__ pts,
    float* __restrict__ out)
{
    const int img = blockIdx.x, t = threadIdx.x;
    __shared__ float sv[NCELL];
    __shared__ float redf[16];

    const float px = pts[(size_t)img*NPTS*2 + t*2 + 0];
    const float py = pts[(size_t)img*NPTS*2 + t*2 + 1];
    int r_lo, c_lo; window_of(px, py, r_lo, c_lo);

    float dx2[7], dy2[7];
#pragma unroll
    for (int j = 0; j < 7; ++j) {
        float dx = px - (float)(8*(c_lo+j) + 4);
        float dy = py - (float)(8*(r_lo+j) + 4);
        dx2[j] = dx*dx; dy2[j] = dy*dy;
    }
    float K[49];
#pragma unroll
    for (int wy = 0; wy < 7; ++wy)
#pragma unroll
        for (int wx = 0; wx < 7; ++wx)
            K[wy*7+wx] = exp2f(C2 * (dx2[wx] + dy2[wy]));

    const int lbase = r_lo*GRID_N + c_lo;
    float breg[16];
    const float4* d4 = (const float4*)(dens + (size_t)img*NCELL + t*16);
#pragma unroll
    for (int j = 0; j < 4; ++j) {
        float4 v = d4[j];
        breg[j*4+0]=v.x; breg[j*4+1]=v.y; breg[j*4+2]=v.z; breg[j*4+3]=v.w;
    }
    const float A = 1.0f/(float)NPTS;
    float u = A;
    float4* sv4 = (float4*)sv;
    for (int it = 0; it < NITER; ++it) {
        __syncthreads();
#pragma unroll
        for (int j = 0; j < 4; ++j) sv4[t*4+j] = make_float4(0.f,0.f,0.f,0.f);
        __syncthreads();
#pragma unroll
        for (int wy = 0; wy < 7; ++wy)
#pragma unroll
            for (int wx = 0; wx < 7; ++wx)
                atomicAdd(&sv[lbase + wy*GRID_N + wx], u * K[wy*7+wx]);
        __syncthreads();
#pragma unroll
        for (int j = 0; j < 16; ++j) { int c = t*16+j; sv[c] = breg[j] / (sv[c] + EPSF); }
        __syncthreads();
        float kv = 0.f;
#pragma unroll
        for (int wy = 0; wy < 7; ++wy)
#pragma unroll
            for (int wx = 0; wx < 7; ++wx)
                kv = fmaf(K[wy*7+wx], sv[lbase + wy*GRID_N + wx], kv);
        u = A / (kv + EPSF);
    }
    float li = 0.f;
#pragma unroll
    for (int wy = 0; wy < 7; ++wy)
#pragma unroll
        for (int wx = 0; wx < 7; ++wx)
            li = fmaf(K[wy*7+wx] * (dx2[wx]+dy2[wy]), sv[lbase + wy*GRID_N + wx], li);
    li *= u;
#pragma unroll
    for (int o = 32; o > 0; o >>= 1) li += __shfl_down(li, o);
    if ((t & 63) == 0) redf[t >> 6] = li;
    __syncthreads();
    if (t == 0) {
        float s = 0.f;
#pragma unroll
        for (int w = 0; w < 16; ++w) s += redf[w];
        atomicAdd(&out[0], s);
        atomicAdd(&out[1], s);
    }
}

extern "C" void kernel_launch(void* const* d_in, const int* in_sizes, int n_in,
                              void* d_out, int out_size, void* d_ws, size_t ws_size,
                              hipStream_t stream)
{
    const float* dens = (const float*)d_in[0];   // [4,1,128,128]
    const float* pts  = (const float*)d_in[2];   // [4,1024,2]
    float* out = (float*)d_out;
    unsigned* ws_u32 = (unsigned*)d_ws;

    if (ws_size < (size_t)WS_TOTAL) {   // insurance: slow-but-correct path
        hipMemsetAsync(d_out, 0, 3*sizeof(float), stream);
        ot_fallback_kernel<<<NIMG, 1024, 0, stream>>>(dens, pts, out);
        return;
    }

    hipMemsetAsync(d_ws, 0, ZERO_BYTES, stream);   // loss+done+gate+u2
    ot_main_kernel<<<NIMG*NBAND, TPB, 0, stream>>>(dens, pts, ws_u32, out);
}